// Round 1
// baseline (598.044 us; speedup 1.0000x reference)
//
#include <hip/hip_runtime.h>

// Sizes (fixed by the problem)
#define BB   8
#define N0   4096
#define N1   1024
#define N2   256
#define GG   1024
#define AFW  32

// ---------------------------------------------------------------------------
// k_y3_enc: y3 partials (x3 @ fp3_w1[:1024,:]) split over 4 K-chunks, plus the
// approach-point encoder (tiny) folded into part==0 blocks.
// grid (8,4) x 256
__global__ void __launch_bounds__(256)
k_y3_enc(const float* __restrict__ x3, const float* __restrict__ w1,
         double* __restrict__ y3p,
         const float* __restrict__ ap,
         const float* __restrict__ ew1, const float* __restrict__ eb1,
         const float* __restrict__ ew2, const float* __restrict__ eb2,
         float* __restrict__ af) {
  __shared__ float hs[32];
  const int b = blockIdx.x, part = blockIdx.y, tid = threadIdx.x;
  double acc = 0.0;
  const float* xr = x3 + (size_t)b * GG + part * 256;
  const float* wr = w1 + (size_t)part * 256 * 256;
  for (int k = 0; k < 256; ++k)
    acc += (double)xr[k] * (double)wr[k * 256 + tid];
  y3p[((size_t)b * 4 + part) * 256 + tid] = acc;

  if (part == 0) {
    if (tid < 32) {
      double a = (double)eb1[tid];
      for (int k = 0; k < 3; ++k)
        a += (double)ap[b * 3 + k] * (double)ew1[k * 32 + tid];
      hs[tid] = fmaxf((float)a, 0.f);
    }
    __syncthreads();
    if (tid < 32) {
      double a = (double)eb2[tid];
      for (int k = 0; k < 32; ++k)
        a += (double)hs[k] * (double)ew2[k * 32 + tid];
      af[b * 32 + tid] = (float)a;
    }
  }
}

// ---------------------------------------------------------------------------
// k_fp3: per (b, n2) point: t = relu(y3 + x2 @ w1[1024:,:] + b1); h2 = t @ w2 + b2
// 8 points/block, 256 threads. grid 256.
__global__ void __launch_bounds__(256)
k_fp3(const float* __restrict__ x2, const double* __restrict__ y3p,
      const float* __restrict__ w1, const float* __restrict__ b1,
      const float* __restrict__ w2, const float* __restrict__ b2,
      float* __restrict__ h2) {
  __shared__ float rows[8][256];
  __shared__ float t[8][256];
  const int b = blockIdx.x >> 5;         // 32 blocks per batch
  const int p0 = (blockIdx.x & 31) * 8;  // point base within batch
  const int tid = threadIdx.x;

  for (int p = 0; p < 8; ++p)
    rows[p][tid] = x2[(((size_t)b * N2) + p0 + p) * 256 + tid];
  __syncthreads();

  {
    const double ybase = y3p[((size_t)b * 4 + 0) * 256 + tid] +
                         y3p[((size_t)b * 4 + 1) * 256 + tid] +
                         y3p[((size_t)b * 4 + 2) * 256 + tid] +
                         y3p[((size_t)b * 4 + 3) * 256 + tid];
    double acc[8];
#pragma unroll
    for (int p = 0; p < 8; ++p) acc[p] = ybase;
    for (int k = 0; k < 256; ++k) {
      const double wv = (double)w1[(size_t)(1024 + k) * 256 + tid];
#pragma unroll
      for (int p = 0; p < 8; ++p) acc[p] += (double)rows[p][k] * wv;
    }
    const double bb = (double)b1[tid];
#pragma unroll
    for (int p = 0; p < 8; ++p) t[p][tid] = fmaxf((float)(acc[p] + bb), 0.f);
  }
  __syncthreads();
  {
    double acc[8];
    const double bb = (double)b2[tid];
#pragma unroll
    for (int p = 0; p < 8; ++p) acc[p] = bb;
    for (int k = 0; k < 256; ++k) {
      const double wv = (double)w2[(size_t)k * 256 + tid];
#pragma unroll
      for (int p = 0; p < 8; ++p) acc[p] += (double)t[p][k] * wv;
    }
#pragma unroll
    for (int p = 0; p < 8; ++p)
      h2[(((size_t)b * N2) + p0 + p) * 256 + tid] = (float)acc[p];
  }
}

// ---------------------------------------------------------------------------
// Brute-force 3-NN: candidates staged in LDS (fp64), one thread per query.
// Stable insertion (strict <) matches top_k tie behavior. Normalized inverse-
// squared-distance weights stored as fp64.
template <int NCAND, int QCHUNKS>
__global__ void __launch_bounds__(256)
k_knn(const float* __restrict__ cpos, const float* __restrict__ qpos,
      int* __restrict__ idxo, double* __restrict__ wno) {
  __shared__ double ps[NCAND * 3];
  const int b = blockIdx.x / QCHUNKS;
  const int q = (blockIdx.x % QCHUNKS) * 256 + threadIdx.x;
  for (int i = threadIdx.x; i < NCAND * 3; i += 256)
    ps[i] = (double)cpos[(size_t)b * NCAND * 3 + i];
  __syncthreads();

  const size_t gq = (size_t)b * (QCHUNKS * 256) + q;
  const double qx = (double)qpos[gq * 3 + 0];
  const double qy = (double)qpos[gq * 3 + 1];
  const double qz = (double)qpos[gq * 3 + 2];

  double d0 = 1e300, d1 = 1e300, d2 = 1e300;
  int i0 = 0, i1 = 0, i2 = 0;
  for (int k = 0; k < NCAND; ++k) {
    const double dx = qx - ps[k * 3 + 0];
    const double dy = qy - ps[k * 3 + 1];
    const double dz = qz - ps[k * 3 + 2];
    const double d = dx * dx + dy * dy + dz * dz;
    if (d < d2) {
      if (d < d1) {
        d2 = d1; i2 = i1;
        if (d < d0) { d1 = d0; i1 = i0; d0 = d; i0 = k; }
        else        { d1 = d;  i1 = k; }
      } else { d2 = d; i2 = k; }
    }
  }
  const double w0 = 1.0 / fmax(d0, 1e-16);
  const double w1 = 1.0 / fmax(d1, 1e-16);
  const double w2 = 1.0 / fmax(d2, 1e-16);
  const double inv = 1.0 / (w0 + w1 + w2);
  idxo[gq * 3 + 0] = i0;
  idxo[gq * 3 + 1] = i1;
  idxo[gq * 3 + 2] = i2;
  wno[gq * 3 + 0] = w0 * inv;
  wno[gq * 3 + 1] = w1 * inv;
  wno[gq * 3 + 2] = w2 * inv;
}

// ---------------------------------------------------------------------------
// k_fp2: interp(h2 via 3-NN) || x1 -> relu(384->256) -> 256->128. 8 pts/block.
__global__ void __launch_bounds__(256)
k_fp2(const float* __restrict__ h2, const float* __restrict__ x1,
      const int* __restrict__ idx2, const double* __restrict__ wn2,
      const float* __restrict__ w1, const float* __restrict__ b1,
      const float* __restrict__ w2, const float* __restrict__ b2,
      float* __restrict__ h1) {
  __shared__ float rows[8][384];
  __shared__ float t[8][256];
  __shared__ int sidx[8][3];
  __shared__ double swn[8][3];
  const int b = blockIdx.x >> 7;          // 128 blocks per batch
  const int p0 = (blockIdx.x & 127) * 8;  // point base within batch (N1)
  const int tid = threadIdx.x;

  if (tid < 24) {
    const int p = tid / 3, i = tid % 3;
    const size_t g = ((size_t)b * N1 + p0 + p) * 3 + i;
    sidx[p][i] = idx2[g];
    swn[p][i] = wn2[g];
  }
  __syncthreads();

  {
    const float* base = h2 + (size_t)b * N2 * 256;
    for (int p = 0; p < 8; ++p) {
      const double v = swn[p][0] * (double)base[(size_t)sidx[p][0] * 256 + tid] +
                       swn[p][1] * (double)base[(size_t)sidx[p][1] * 256 + tid] +
                       swn[p][2] * (double)base[(size_t)sidx[p][2] * 256 + tid];
      rows[p][tid] = (float)v;
    }
    if (tid < 128) {
      for (int p = 0; p < 8; ++p)
        rows[p][256 + tid] = x1[((size_t)b * N1 + p0 + p) * 128 + tid];
    }
  }
  __syncthreads();

  {
    double acc[8];
    const double bb = (double)b1[tid];
#pragma unroll
    for (int p = 0; p < 8; ++p) acc[p] = bb;
    for (int k = 0; k < 384; ++k) {
      const double wv = (double)w1[(size_t)k * 256 + tid];
#pragma unroll
      for (int p = 0; p < 8; ++p) acc[p] += (double)rows[p][k] * wv;
    }
#pragma unroll
    for (int p = 0; p < 8; ++p) t[p][tid] = fmaxf((float)acc[p], 0.f);
  }
  __syncthreads();

  {
    const int j = tid & 127, pb = (tid >> 7) * 4;
    double acc[4];
    const double bb = (double)b2[j];
#pragma unroll
    for (int p = 0; p < 4; ++p) acc[p] = bb;
    for (int k = 0; k < 256; ++k) {
      const double wv = (double)w2[(size_t)k * 128 + j];
#pragma unroll
      for (int p = 0; p < 4; ++p) acc[p] += (double)t[pb + p][k] * wv;
    }
#pragma unroll
    for (int p = 0; p < 4; ++p)
      h1[((size_t)b * N1 + p0 + pb + p) * 128 + j] = (float)acc[p];
  }
}

// ---------------------------------------------------------------------------
// Generic 128-wide MLP layer: 16 points/block, 256 threads = 128 j x 2 point
// groups of 8; fp64 accumulation; LDS in/out with compile-time strides.
template <int K, int INS, int OUTS>
__device__ __forceinline__ void mlp_layer(const float* in, float* out,
                                          const float* __restrict__ w,
                                          const float* __restrict__ bias,
                                          bool do_relu, int tid) {
  const int j = tid & 127;
  const int pb = (tid >> 7) * 8;
  double acc[8];
  const double bj = (double)bias[j];
#pragma unroll
  for (int p = 0; p < 8; ++p) acc[p] = bj;
  for (int k = 0; k < K; ++k) {
    const double wv = (double)w[(size_t)k * 128 + j];
#pragma unroll
    for (int p = 0; p < 8; ++p)
      acc[p] += (double)in[(pb + p) * INS + k] * wv;
  }
#pragma unroll
  for (int p = 0; p < 8; ++p) {
    float v = (float)acc[p];
    out[(pb + p) * OUTS + j] = do_relu ? fmaxf(v, 0.f) : v;
  }
}

// k_fp1head: interp(h1)||pos0 -> 131->128 relu -> 128 relu -> 128 ->
//            concat af -> 160->128 relu -> 128 relu -> 128->1
__global__ void __launch_bounds__(256)
k_fp1head(const float* __restrict__ h1, const float* __restrict__ pos0,
          const int* __restrict__ idx1, const double* __restrict__ wn1,
          const float* __restrict__ afv,
          const float* __restrict__ w1, const float* __restrict__ b1,
          const float* __restrict__ w2, const float* __restrict__ b2,
          const float* __restrict__ w3, const float* __restrict__ b3,
          const float* __restrict__ hw1, const float* __restrict__ hb1,
          const float* __restrict__ hw2, const float* __restrict__ hb2,
          const float* __restrict__ hw3, const float* __restrict__ hb3,
          float* __restrict__ out) {
  __shared__ float A[16][132];
  __shared__ float Bf[16][160];
  __shared__ int sidx[16][3];
  __shared__ double swn[16][3];
  __shared__ float af_s[32];
  const int b = blockIdx.x >> 8;          // 256 blocks per batch
  const int p0 = (blockIdx.x & 255) * 16; // point base within batch (N0)
  const int tid = threadIdx.x;

  if (tid < 48) {
    const int p = tid / 3, i = tid % 3;
    const size_t g = ((size_t)b * N0 + p0 + p) * 3 + i;
    sidx[p][i] = idx1[g];
    swn[p][i] = wn1[g];
  }
  if (tid >= 64 && tid < 96) af_s[tid - 64] = afv[b * 32 + (tid - 64)];
  __syncthreads();

  {
    const int c = tid & 127;
    const float* base = h1 + (size_t)b * N1 * 128;
    for (int p = (tid >> 7); p < 16; p += 2) {
      const double v = swn[p][0] * (double)base[(size_t)sidx[p][0] * 128 + c] +
                       swn[p][1] * (double)base[(size_t)sidx[p][1] * 128 + c] +
                       swn[p][2] * (double)base[(size_t)sidx[p][2] * 128 + c];
      A[p][c] = (float)v;
    }
  }
  if (tid < 48) {
    const int p = tid / 3, i = tid % 3;
    A[p][128 + i] = pos0[((size_t)b * N0 + p0 + p) * 3 + i];
  }
  __syncthreads();

  mlp_layer<131, 132, 160>(&A[0][0], &Bf[0][0], w1, b1, true, tid);
  __syncthreads();
  mlp_layer<128, 160, 132>(&Bf[0][0], &A[0][0], w2, b2, true, tid);
  __syncthreads();
  mlp_layer<128, 132, 160>(&A[0][0], &Bf[0][0], w3, b3, false, tid);
  // concat approach features into Bf[:,128:160]
  for (int x = tid; x < 16 * 32; x += 256)
    Bf[x >> 5][128 + (x & 31)] = af_s[x & 31];
  __syncthreads();
  mlp_layer<160, 160, 132>(&Bf[0][0], &A[0][0], hw1, hb1, true, tid);
  __syncthreads();
  mlp_layer<128, 132, 160>(&A[0][0], &Bf[0][0], hw2, hb2, true, tid);
  __syncthreads();

  {
    const int p = tid >> 4, l = tid & 15;
    double acc = 0.0;
    for (int k = l; k < 128; k += 16)
      acc += (double)Bf[p][k] * (double)hw3[k];
    for (int off = 8; off > 0; off >>= 1)
      acc += __shfl_down(acc, off, 16);
    if (l == 0)
      out[(size_t)b * N0 + p0 + p] = (float)(acc + (double)hb3[0]);
  }
}

// ---------------------------------------------------------------------------
extern "C" void kernel_launch(void* const* d_in, const int* in_sizes, int n_in,
                              void* d_out, int out_size, void* d_ws, size_t ws_size,
                              hipStream_t stream) {
  const float* pos0 = (const float*)d_in[0];
  const float* x1   = (const float*)d_in[1];
  const float* pos1 = (const float*)d_in[2];
  const float* x2   = (const float*)d_in[3];
  const float* pos2 = (const float*)d_in[4];
  const float* x3   = (const float*)d_in[5];
  /* d_in[6] = pos3: unused (k=1 interp from a single point is a broadcast) */
  const float* ap   = (const float*)d_in[7];
  const float* fp3w1 = (const float*)d_in[8];
  const float* fp3b1 = (const float*)d_in[9];
  const float* fp3w2 = (const float*)d_in[10];
  const float* fp3b2 = (const float*)d_in[11];
  const float* fp2w1 = (const float*)d_in[12];
  const float* fp2b1 = (const float*)d_in[13];
  const float* fp2w2 = (const float*)d_in[14];
  const float* fp2b2 = (const float*)d_in[15];
  const float* fp1w1 = (const float*)d_in[16];
  const float* fp1b1 = (const float*)d_in[17];
  const float* fp1w2 = (const float*)d_in[18];
  const float* fp1b2 = (const float*)d_in[19];
  const float* fp1w3 = (const float*)d_in[20];
  const float* fp1b3 = (const float*)d_in[21];
  const float* encw1 = (const float*)d_in[22];
  const float* encb1 = (const float*)d_in[23];
  const float* encw2 = (const float*)d_in[24];
  const float* encb2 = (const float*)d_in[25];
  const float* hw1 = (const float*)d_in[26];
  const float* hb1 = (const float*)d_in[27];
  const float* hw2 = (const float*)d_in[28];
  const float* hb2 = (const float*)d_in[29];
  const float* hw3 = (const float*)d_in[30];
  const float* hb3 = (const float*)d_in[31];
  float* out = (float*)d_out;

  char* p = (char*)d_ws;
  double* y3p = (double*)p; p += (size_t)BB * 4 * 256 * 8;
  double* wn2 = (double*)p; p += (size_t)BB * N1 * 3 * 8;
  double* wn1 = (double*)p; p += (size_t)BB * N0 * 3 * 8;
  float*  af  = (float*)p;  p += (size_t)BB * 32 * 4;
  int*    idx2= (int*)p;    p += (size_t)BB * N1 * 3 * 4;
  int*    idx1= (int*)p;    p += (size_t)BB * N0 * 3 * 4;
  float*  h2  = (float*)p;  p += (size_t)BB * N2 * 256 * 4;
  float*  h1  = (float*)p;  p += (size_t)BB * N1 * 128 * 4;

  hipLaunchKernelGGL(k_y3_enc, dim3(BB, 4), dim3(256), 0, stream,
                     x3, fp3w1, y3p, ap, encw1, encb1, encw2, encb2, af);
  hipLaunchKernelGGL(k_fp3, dim3(BB * N2 / 8), dim3(256), 0, stream,
                     x2, y3p, fp3w1, fp3b1, fp3w2, fp3b2, h2);
  hipLaunchKernelGGL((k_knn<N2, N1 / 256>), dim3(BB * N1 / 256), dim3(256), 0, stream,
                     pos2, pos1, idx2, wn2);
  hipLaunchKernelGGL(k_fp2, dim3(BB * N1 / 8), dim3(256), 0, stream,
                     h2, x1, idx2, wn2, fp2w1, fp2b1, fp2w2, fp2b2, h1);
  hipLaunchKernelGGL((k_knn<N1, N0 / 256>), dim3(BB * N0 / 256), dim3(256), 0, stream,
                     pos1, pos0, idx1, wn1);
  hipLaunchKernelGGL(k_fp1head, dim3(BB * N0 / 16), dim3(256), 0, stream,
                     h1, pos0, idx1, wn1, af,
                     fp1w1, fp1b1, fp1w2, fp1b2, fp1w3, fp1b3,
                     hw1, hb1, hw2, hb2, hw3, hb3, out);
}

// Round 3
// 534.940 us; speedup vs baseline: 1.1180x; 1.1180x over previous
//
#include <hip/hip_runtime.h>

// Sizes (fixed by the problem)
#define BB   8
#define N0   4096
#define N1   1024
#define N2   256
#define GG   1024
#define AFW  32

typedef unsigned long long u64;

// ---------------------------------------------------------------------------
// k_y3_enc: y3 partials (x3 @ fp3_w1[:1024,:]) split over 4 K-chunks (fp64),
// plus the approach-point encoder folded into part==0 blocks. grid (8,4) x 256
__global__ void __launch_bounds__(256)
k_y3_enc(const float* __restrict__ x3, const float* __restrict__ w1,
         double* __restrict__ y3p,
         const float* __restrict__ ap,
         const float* __restrict__ ew1, const float* __restrict__ eb1,
         const float* __restrict__ ew2, const float* __restrict__ eb2,
         float* __restrict__ af) {
  __shared__ float hs[32];
  const int b = blockIdx.x, part = blockIdx.y, tid = threadIdx.x;
  double acc = 0.0;
  const float* xr = x3 + (size_t)b * GG + part * 256;
  const float* wr = w1 + (size_t)part * 256 * 256;
  for (int k = 0; k < 256; ++k)
    acc += (double)xr[k] * (double)wr[k * 256 + tid];
  y3p[((size_t)b * 4 + part) * 256 + tid] = acc;

  if (part == 0) {
    if (tid < 32) {
      double a = (double)eb1[tid];
      for (int k = 0; k < 3; ++k)
        a += (double)ap[b * 3 + k] * (double)ew1[k * 32 + tid];
      hs[tid] = fmaxf((float)a, 0.f);
    }
    __syncthreads();
    if (tid < 32) {
      double a = (double)eb2[tid];
      for (int k = 0; k < 32; ++k)
        a += (double)hs[k] * (double)ew2[k * 32 + tid];
      af[b * 32 + tid] = (float)a;
    }
  }
}

// ---------------------------------------------------------------------------
// Branchless single-kernel 3-NN: one thread per query, all NCAND candidates
// staged in LDS as fp64. Keys = fp64 distance bits with low 10 mantissa bits
// replaced by candidate index (monotone; stable tie-break = lower index;
// 2^-42 relative perturbation). fp64 normalized inverse-d2 weights out.
template <int NCAND, int QTOT>
__global__ void __launch_bounds__(256)
k_knn(const float* __restrict__ cpos, const float* __restrict__ qpos,
      int* __restrict__ idxo, double* __restrict__ wno) {
  __shared__ double ps[NCAND * 3];
  const int qc = blockIdx.x % (QTOT / 256);
  const int b = blockIdx.x / (QTOT / 256);
  const int tid = threadIdx.x;
  {
    const float* src = cpos + (size_t)b * NCAND * 3;
    for (int i = tid; i < NCAND * 3; i += 256) ps[i] = (double)src[i];
  }
  __syncthreads();

  const int q = qc * 256 + tid;
  const size_t gq = (size_t)b * QTOT + q;
  const double qx = (double)qpos[gq * 3 + 0];
  const double qy = (double)qpos[gq * 3 + 1];
  const double qz = (double)qpos[gq * 3 + 2];

  u64 k0 = ~0ull, k1 = ~0ull, k2 = ~0ull;
#pragma unroll 4
  for (int k = 0; k < NCAND; ++k) {
    const double dx = qx - ps[3 * k + 0];
    const double dy = qy - ps[3 * k + 1];
    const double dz = qz - ps[3 * k + 2];
    const double d = dx * dx + dy * dy + dz * dz;
    const u64 key = (((u64)__double_as_longlong(d)) & ~1023ull) | (unsigned)k;
    const bool c0 = key < k0, c1 = key < k1, c2 = key < k2;
    const u64 n2 = c1 ? k1 : (c2 ? key : k2);
    const u64 n1 = c0 ? k0 : (c1 ? key : k1);
    k0 = c0 ? key : k0; k1 = n1; k2 = n2;
  }
  const double d0 = __longlong_as_double((long long)(k0 & ~1023ull));
  const double d1 = __longlong_as_double((long long)(k1 & ~1023ull));
  const double d2 = __longlong_as_double((long long)(k2 & ~1023ull));
  const double w0 = 1.0 / fmax(d0, 1e-16);
  const double w1 = 1.0 / fmax(d1, 1e-16);
  const double w2 = 1.0 / fmax(d2, 1e-16);
  const double inv = 1.0 / (w0 + w1 + w2);
  idxo[gq * 3 + 0] = (int)(k0 & 1023ull);
  idxo[gq * 3 + 1] = (int)(k1 & 1023ull);
  idxo[gq * 3 + 2] = (int)(k2 & 1023ull);
  wno[gq * 3 + 0] = w0 * inv;
  wno[gq * 3 + 1] = w1 * inv;
  wno[gq * 3 + 2] = w2 * inv;
}

// ---------------------------------------------------------------------------
// k_fp3 (fp64 acc, float4 LDS): t = relu(y3 + x2 @ w1[1024:,:] + b1);
// h2 = t @ w2 + b2. 8 points/block, 256 threads (j = tid). grid 256.
__global__ void __launch_bounds__(256)
k_fp3(const float* __restrict__ x2, const double* __restrict__ y3p,
      const float* __restrict__ w1, const float* __restrict__ b1,
      const float* __restrict__ w2, const float* __restrict__ b2,
      float* __restrict__ h2) {
  __shared__ __align__(16) float rows[8][256];
  __shared__ __align__(16) float t[8][256];
  const int b = blockIdx.x >> 5;
  const int p0 = (blockIdx.x & 31) * 8;
  const int tid = threadIdx.x;

  for (int p = 0; p < 8; ++p)
    rows[p][tid] = x2[(((size_t)b * N2) + p0 + p) * 256 + tid];
  __syncthreads();

  {
    const double ybase = y3p[((size_t)b * 4 + 0) * 256 + tid] +
                         y3p[((size_t)b * 4 + 1) * 256 + tid] +
                         y3p[((size_t)b * 4 + 2) * 256 + tid] +
                         y3p[((size_t)b * 4 + 3) * 256 + tid];
    double acc[8];
#pragma unroll
    for (int p = 0; p < 8; ++p) acc[p] = ybase;
    const float* wj = w1 + (size_t)1024 * 256 + tid;
    for (int k4 = 0; k4 < 64; ++k4) {
      const double w0 = (double)wj[(4 * k4 + 0) * 256];
      const double w1v = (double)wj[(4 * k4 + 1) * 256];
      const double w2v = (double)wj[(4 * k4 + 2) * 256];
      const double w3v = (double)wj[(4 * k4 + 3) * 256];
#pragma unroll
      for (int p = 0; p < 8; ++p) {
        const float4 v = *(const float4*)(&rows[p][4 * k4]);
        acc[p] += (double)v.x * w0;
        acc[p] += (double)v.y * w1v;
        acc[p] += (double)v.z * w2v;
        acc[p] += (double)v.w * w3v;
      }
    }
    const double bb = (double)b1[tid];
#pragma unroll
    for (int p = 0; p < 8; ++p) t[p][tid] = fmaxf((float)(acc[p] + bb), 0.f);
  }
  __syncthreads();
  {
    double acc[8];
    const double bb = (double)b2[tid];
#pragma unroll
    for (int p = 0; p < 8; ++p) acc[p] = bb;
    const float* wj = w2 + tid;
    for (int k4 = 0; k4 < 64; ++k4) {
      const double w0 = (double)wj[(4 * k4 + 0) * 256];
      const double w1v = (double)wj[(4 * k4 + 1) * 256];
      const double w2v = (double)wj[(4 * k4 + 2) * 256];
      const double w3v = (double)wj[(4 * k4 + 3) * 256];
#pragma unroll
      for (int p = 0; p < 8; ++p) {
        const float4 v = *(const float4*)(&t[p][4 * k4]);
        acc[p] += (double)v.x * w0;
        acc[p] += (double)v.y * w1v;
        acc[p] += (double)v.z * w2v;
        acc[p] += (double)v.w * w3v;
      }
    }
#pragma unroll
    for (int p = 0; p < 8; ++p)
      h2[(((size_t)b * N2) + p0 + p) * 256 + tid] = (float)acc[p];
  }
}

// ---------------------------------------------------------------------------
// k_fp2 (fp64 acc): interp(h2, k=3) || x1 -> relu(384->256) -> 256->128.
__global__ void __launch_bounds__(256)
k_fp2(const float* __restrict__ h2, const float* __restrict__ x1,
      const int* __restrict__ idx2, const double* __restrict__ wn2,
      const float* __restrict__ w1, const float* __restrict__ b1,
      const float* __restrict__ w2, const float* __restrict__ b2,
      float* __restrict__ h1) {
  __shared__ __align__(16) float rows[8][384];
  __shared__ __align__(16) float t[8][256];
  __shared__ int sidx[8][3];
  __shared__ double swn[8][3];
  const int b = blockIdx.x >> 7;
  const int p0 = (blockIdx.x & 127) * 8;
  const int tid = threadIdx.x;

  if (tid < 24) {
    const int p = tid / 3, i = tid % 3;
    const size_t g = ((size_t)b * N1 + p0 + p) * 3 + i;
    sidx[p][i] = idx2[g];
    swn[p][i] = wn2[g];
  }
  __syncthreads();

  {
    const float* base = h2 + (size_t)b * N2 * 256;
    for (int p = 0; p < 8; ++p) {
      const double v = swn[p][0] * (double)base[(size_t)sidx[p][0] * 256 + tid] +
                       swn[p][1] * (double)base[(size_t)sidx[p][1] * 256 + tid] +
                       swn[p][2] * (double)base[(size_t)sidx[p][2] * 256 + tid];
      rows[p][tid] = (float)v;
    }
    if (tid < 128) {
      for (int p = 0; p < 8; ++p)
        rows[p][256 + tid] = x1[((size_t)b * N1 + p0 + p) * 128 + tid];
    }
  }
  __syncthreads();

  {
    double acc[8];
    const double bb = (double)b1[tid];
#pragma unroll
    for (int p = 0; p < 8; ++p) acc[p] = bb;
    const float* wj = w1 + tid;
    for (int k4 = 0; k4 < 96; ++k4) {
      const double w0 = (double)wj[(4 * k4 + 0) * 256];
      const double w1v = (double)wj[(4 * k4 + 1) * 256];
      const double w2v = (double)wj[(4 * k4 + 2) * 256];
      const double w3v = (double)wj[(4 * k4 + 3) * 256];
#pragma unroll
      for (int p = 0; p < 8; ++p) {
        const float4 v = *(const float4*)(&rows[p][4 * k4]);
        acc[p] += (double)v.x * w0;
        acc[p] += (double)v.y * w1v;
        acc[p] += (double)v.z * w2v;
        acc[p] += (double)v.w * w3v;
      }
    }
#pragma unroll
    for (int p = 0; p < 8; ++p) t[p][tid] = fmaxf((float)acc[p], 0.f);
  }
  __syncthreads();

  {
    const int j = tid & 127, pb = (tid >> 7) * 4;
    double acc[4];
    const double bb = (double)b2[j];
#pragma unroll
    for (int p = 0; p < 4; ++p) acc[p] = bb;
    const float* wj = w2 + j;
    for (int k4 = 0; k4 < 64; ++k4) {
      const double w0 = (double)wj[(4 * k4 + 0) * 128];
      const double w1v = (double)wj[(4 * k4 + 1) * 128];
      const double w2v = (double)wj[(4 * k4 + 2) * 128];
      const double w3v = (double)wj[(4 * k4 + 3) * 128];
#pragma unroll
      for (int p = 0; p < 4; ++p) {
        const float4 v = *(const float4*)(&t[pb + p][4 * k4]);
        acc[p] += (double)v.x * w0;
        acc[p] += (double)v.y * w1v;
        acc[p] += (double)v.z * w2v;
        acc[p] += (double)v.w * w3v;
      }
    }
#pragma unroll
    for (int p = 0; p < 4; ++p)
      h1[((size_t)b * N1 + p0 + pb + p) * 128 + j] = (float)acc[p];
  }
}

// ---------------------------------------------------------------------------
// fp64-acc MLP layer, 128-wide: 16 points/block, 256 threads = 128 j x 2
// halves of 8 points; float4 LDS broadcast reads, per-k sequential FMA order.
template <int K4, int TAIL, int INS, int OUTS, bool RELU>
__device__ __forceinline__ void mlp128(const float* in, float* out,
                                       const float* __restrict__ w,
                                       const float* __restrict__ bias, int tid) {
  const int j = tid & 127;
  const int pb = (tid >> 7) * 8;
  double acc[8];
  const double bj = (double)bias[j];
#pragma unroll
  for (int p = 0; p < 8; ++p) acc[p] = bj;
  const float* wj = w + j;
  for (int k4 = 0; k4 < K4; ++k4) {
    const double w0 = (double)wj[(4 * k4 + 0) * 128];
    const double w1v = (double)wj[(4 * k4 + 1) * 128];
    const double w2v = (double)wj[(4 * k4 + 2) * 128];
    const double w3v = (double)wj[(4 * k4 + 3) * 128];
#pragma unroll
    for (int p = 0; p < 8; ++p) {
      const float4 v = *(const float4*)(in + (pb + p) * INS + 4 * k4);
      acc[p] += (double)v.x * w0;
      acc[p] += (double)v.y * w1v;
      acc[p] += (double)v.z * w2v;
      acc[p] += (double)v.w * w3v;
    }
  }
#pragma unroll
  for (int k = K4 * 4; k < K4 * 4 + TAIL; ++k) {
    const double wv = (double)wj[k * 128];
#pragma unroll
    for (int p = 0; p < 8; ++p) acc[p] += (double)in[(pb + p) * INS + k] * wv;
  }
#pragma unroll
  for (int p = 0; p < 8; ++p) {
    const float v = (float)acc[p];
    out[(pb + p) * OUTS + j] = RELU ? fmaxf(v, 0.f) : v;
  }
}

// k_fp1head: interp(h1)||pos0 -> [131->128 r] -> [128 r] -> [128] -> cat af ->
//            [160->128 r] -> [128 r] -> [128->1]  (all fp64 accumulation)
__global__ void __launch_bounds__(256)
k_fp1head(const float* __restrict__ h1, const float* __restrict__ pos0,
          const int* __restrict__ idx1, const double* __restrict__ wn1,
          const float* __restrict__ afv,
          const float* __restrict__ w1, const float* __restrict__ b1,
          const float* __restrict__ w2, const float* __restrict__ b2,
          const float* __restrict__ w3, const float* __restrict__ b3,
          const float* __restrict__ hw1, const float* __restrict__ hb1,
          const float* __restrict__ hw2, const float* __restrict__ hb2,
          const float* __restrict__ hw3, const float* __restrict__ hb3,
          float* __restrict__ out) {
  __shared__ __align__(16) float A[16][132];
  __shared__ __align__(16) float Bf[16][160];
  __shared__ int sidx[16][3];
  __shared__ double swn[16][3];
  __shared__ float af_s[32];
  const int b = blockIdx.x >> 8;
  const int p0 = (blockIdx.x & 255) * 16;
  const int tid = threadIdx.x;

  if (tid < 48) {
    const int p = tid / 3, i = tid % 3;
    const size_t g = ((size_t)b * N0 + p0 + p) * 3 + i;
    sidx[p][i] = idx1[g];
    swn[p][i] = wn1[g];
  }
  if (tid >= 64 && tid < 96) af_s[tid - 64] = afv[b * 32 + (tid - 64)];
  __syncthreads();

  {
    const int c = tid & 127;
    const float* base = h1 + (size_t)b * N1 * 128;
    for (int p = (tid >> 7); p < 16; p += 2) {
      const double v = swn[p][0] * (double)base[(size_t)sidx[p][0] * 128 + c] +
                       swn[p][1] * (double)base[(size_t)sidx[p][1] * 128 + c] +
                       swn[p][2] * (double)base[(size_t)sidx[p][2] * 128 + c];
      A[p][c] = (float)v;
    }
  }
  if (tid < 48) {
    const int p = tid / 3, i = tid % 3;
    A[p][128 + i] = pos0[((size_t)b * N0 + p0 + p) * 3 + i];
  }
  __syncthreads();

  mlp128<32, 3, 132, 160, true>(&A[0][0], &Bf[0][0], w1, b1, tid);
  __syncthreads();
  mlp128<32, 0, 160, 132, true>(&Bf[0][0], &A[0][0], w2, b2, tid);
  __syncthreads();
  mlp128<32, 0, 132, 160, false>(&A[0][0], &Bf[0][0], w3, b3, tid);
  for (int x = tid; x < 16 * 32; x += 256)
    Bf[x >> 5][128 + (x & 31)] = af_s[x & 31];
  __syncthreads();
  mlp128<40, 0, 160, 132, true>(&Bf[0][0], &A[0][0], hw1, hb1, tid);
  __syncthreads();
  mlp128<32, 0, 132, 160, true>(&A[0][0], &Bf[0][0], hw2, hb2, tid);
  __syncthreads();

  // head3: fp64 dot, 16 lanes per point
  {
    const int p = tid >> 4, l = tid & 15;
    double acc = 0.0;
    for (int k = l; k < 128; k += 16)
      acc += (double)Bf[p][k] * (double)hw3[k];
    for (int off = 8; off > 0; off >>= 1)
      acc += __shfl_down(acc, off, 16);
    if (l == 0)
      out[(size_t)b * N0 + p0 + p] = (float)(acc + (double)hb3[0]);
  }
}

// ---------------------------------------------------------------------------
extern "C" void kernel_launch(void* const* d_in, const int* in_sizes, int n_in,
                              void* d_out, int out_size, void* d_ws, size_t ws_size,
                              hipStream_t stream) {
  const float* pos0 = (const float*)d_in[0];
  const float* x1   = (const float*)d_in[1];
  const float* pos1 = (const float*)d_in[2];
  const float* x2   = (const float*)d_in[3];
  const float* pos2 = (const float*)d_in[4];
  const float* x3   = (const float*)d_in[5];
  /* d_in[6] = pos3: unused (k=1 interp from a single point is a broadcast) */
  const float* ap   = (const float*)d_in[7];
  const float* fp3w1 = (const float*)d_in[8];
  const float* fp3b1 = (const float*)d_in[9];
  const float* fp3w2 = (const float*)d_in[10];
  const float* fp3b2 = (const float*)d_in[11];
  const float* fp2w1 = (const float*)d_in[12];
  const float* fp2b1 = (const float*)d_in[13];
  const float* fp2w2 = (const float*)d_in[14];
  const float* fp2b2 = (const float*)d_in[15];
  const float* fp1w1 = (const float*)d_in[16];
  const float* fp1b1 = (const float*)d_in[17];
  const float* fp1w2 = (const float*)d_in[18];
  const float* fp1b2 = (const float*)d_in[19];
  const float* fp1w3 = (const float*)d_in[20];
  const float* fp1b3 = (const float*)d_in[21];
  const float* encw1 = (const float*)d_in[22];
  const float* encb1 = (const float*)d_in[23];
  const float* encw2 = (const float*)d_in[24];
  const float* encb2 = (const float*)d_in[25];
  const float* hw1 = (const float*)d_in[26];
  const float* hb1 = (const float*)d_in[27];
  const float* hw2 = (const float*)d_in[28];
  const float* hb2 = (const float*)d_in[29];
  const float* hw3 = (const float*)d_in[30];
  const float* hb3 = (const float*)d_in[31];
  float* out = (float*)d_out;

  // Alias-free layout; total 7,832,576 B (== round-1's proven footprint).
  char* p = (char*)d_ws;
  double* y3p = (double*)p; p += (size_t)BB * 4 * 256 * 8;   // 64 KB
  double* wn2 = (double*)p; p += (size_t)BB * N1 * 3 * 8;    // 192 KB
  double* wn1 = (double*)p; p += (size_t)BB * N0 * 3 * 8;    // 768 KB
  float*  af  = (float*)p;  p += (size_t)BB * 32 * 4;        // 1 KB
  int*    idx2= (int*)p;    p += (size_t)BB * N1 * 3 * 4;    // 96 KB
  int*    idx1= (int*)p;    p += (size_t)BB * N0 * 3 * 4;    // 384 KB
  float*  h2  = (float*)p;  p += (size_t)BB * N2 * 256 * 4;  // 2 MB
  float*  h1  = (float*)p;  p += (size_t)BB * N1 * 128 * 4;  // 4 MB

  hipLaunchKernelGGL(k_y3_enc, dim3(BB, 4), dim3(256), 0, stream,
                     x3, fp3w1, y3p, ap, encw1, encb1, encw2, encb2, af);
  hipLaunchKernelGGL((k_knn<N2, N1>), dim3(BB * (N1 / 256)), dim3(256), 0, stream,
                     pos2, pos1, idx2, wn2);
  hipLaunchKernelGGL((k_knn<N1, N0>), dim3(BB * (N0 / 256)), dim3(256), 0, stream,
                     pos1, pos0, idx1, wn1);
  hipLaunchKernelGGL(k_fp3, dim3(BB * N2 / 8), dim3(256), 0, stream,
                     x2, y3p, fp3w1, fp3b1, fp3w2, fp3b2, h2);
  hipLaunchKernelGGL(k_fp2, dim3(BB * N1 / 8), dim3(256), 0, stream,
                     h2, x1, idx2, wn2, fp2w1, fp2b1, fp2w2, fp2b2, h1);
  hipLaunchKernelGGL(k_fp1head, dim3(BB * N0 / 16), dim3(256), 0, stream,
                     h1, pos0, idx1, wn1, af,
                     fp1w1, fp1b1, fp1w2, fp1b2, fp1w3, fp1b3,
                     hw1, hb1, hw2, hb2, hw3, hb3, out);
}

// Round 4
// 423.596 us; speedup vs baseline: 1.4118x; 1.2629x over previous
//
#include <hip/hip_runtime.h>

// Sizes (fixed by the problem)
#define BB   8
#define N0   4096
#define N1   1024
#define N2   256
#define GG   1024
#define AFW  32

typedef unsigned long long u64;

// ---------------------------------------------------------------------------
// Branchless top-3 insert on u64 keys (distance bits | index), stable.
__device__ __forceinline__ void ins3(u64 key, u64& k0, u64& k1, u64& k2) {
  const bool c0 = key < k0, c1 = key < k1, c2 = key < k2;
  const u64 n2 = c1 ? k1 : (c2 ? key : k2);
  const u64 n1 = c0 ? k0 : (c1 ? key : k1);
  k0 = c0 ? key : k0; k1 = n1; k2 = n2;
}

// ---------------------------------------------------------------------------
// k_y3_enc: y3 partials (x3 @ fp3_w1[:1024,:]) split over 4 K-chunks (fp64),
// plus the approach-point encoder folded into part==0 blocks. grid (8,4) x 256
__global__ void __launch_bounds__(256)
k_y3_enc(const float* __restrict__ x3, const float* __restrict__ w1,
         double* __restrict__ y3p,
         const float* __restrict__ ap,
         const float* __restrict__ ew1, const float* __restrict__ eb1,
         const float* __restrict__ ew2, const float* __restrict__ eb2,
         float* __restrict__ af) {
  __shared__ double hs[32];
  const int b = blockIdx.x, part = blockIdx.y, tid = threadIdx.x;
  double acc = 0.0;
  const float* xr = x3 + (size_t)b * GG + part * 256;
  const float* wr = w1 + (size_t)part * 256 * 256;
  for (int k = 0; k < 256; ++k)
    acc += (double)xr[k] * (double)wr[k * 256 + tid];
  y3p[((size_t)b * 4 + part) * 256 + tid] = acc;

  if (part == 0) {
    if (tid < 32) {
      double a = (double)eb1[tid];
      for (int k = 0; k < 3; ++k)
        a += (double)ap[b * 3 + k] * (double)ew1[k * 32 + tid];
      hs[tid] = fmax(a, 0.0);
    }
    __syncthreads();
    if (tid < 32) {
      double a = (double)eb2[tid];
      for (int k = 0; k < 32; ++k)
        a += hs[k] * (double)ew2[k * 32 + tid];
      af[b * 32 + tid] = (float)a;
    }
  }
}

// ---------------------------------------------------------------------------
// 4-wave-split branchless 3-NN: block = 64 queries x 4 waves; wave w scans
// candidate quarter w, then wave 0 merges the 12 keys (order-independent:
// keys are unique). Keys = fp64 d2 bits with low 10 mantissa bits replaced by
// candidate index (monotone; stable tie-break; 2^-42 relative perturbation).
template <int NCAND, int QTOT>
__global__ void __launch_bounds__(256)
k_knn4(const float* __restrict__ cpos, const float* __restrict__ qpos,
       int* __restrict__ idxo, double* __restrict__ wno) {
  __shared__ double ps[NCAND * 3];
  __shared__ u64 topw[4][64][3];
  const int qc = blockIdx.x % (QTOT / 64);
  const int b = blockIdx.x / (QTOT / 64);
  const int tid = threadIdx.x;
  {
    const float* src = cpos + (size_t)b * NCAND * 3;
    for (int i = tid; i < NCAND * 3; i += 256) ps[i] = (double)src[i];
  }
  __syncthreads();

  const int wave = tid >> 6, lane = tid & 63;
  const size_t gq = (size_t)b * QTOT + qc * 64 + lane;
  const double qx = (double)qpos[gq * 3 + 0];
  const double qy = (double)qpos[gq * 3 + 1];
  const double qz = (double)qpos[gq * 3 + 2];

  constexpr int NC4 = NCAND / 4;
  u64 k0 = ~0ull, k1 = ~0ull, k2 = ~0ull;
  const int kbeg = wave * NC4;
#pragma unroll 2
  for (int kk = 0; kk < NC4; ++kk) {
    const int k = kbeg + kk;
    const double dx = qx - ps[3 * k + 0];
    const double dy = qy - ps[3 * k + 1];
    const double dz = qz - ps[3 * k + 2];
    const double d = dx * dx + dy * dy + dz * dz;
    const u64 key = (((u64)__double_as_longlong(d)) & ~1023ull) | (unsigned)k;
    ins3(key, k0, k1, k2);
  }
  topw[wave][lane][0] = k0; topw[wave][lane][1] = k1; topw[wave][lane][2] = k2;
  __syncthreads();

  if (tid < 64) {
    u64 m0 = ~0ull, m1 = ~0ull, m2 = ~0ull;
#pragma unroll
    for (int w = 0; w < 4; ++w)
#pragma unroll
      for (int s = 0; s < 3; ++s)
        ins3(topw[w][tid][s], m0, m1, m2);
    const double d0 = __longlong_as_double((long long)(m0 & ~1023ull));
    const double d1 = __longlong_as_double((long long)(m1 & ~1023ull));
    const double d2 = __longlong_as_double((long long)(m2 & ~1023ull));
    const double w0 = 1.0 / fmax(d0, 1e-16);
    const double w1 = 1.0 / fmax(d1, 1e-16);
    const double w2 = 1.0 / fmax(d2, 1e-16);
    const double inv = 1.0 / (w0 + w1 + w2);
    const size_t go = (size_t)b * QTOT + qc * 64 + tid;
    idxo[go * 3 + 0] = (int)(m0 & 1023ull);
    idxo[go * 3 + 1] = (int)(m1 & 1023ull);
    idxo[go * 3 + 2] = (int)(m2 & 1023ull);
    wno[go * 3 + 0] = w0 * inv;
    wno[go * 3 + 1] = w1 * inv;
    wno[go * 3 + 2] = w2 * inv;
  }
}

// ---------------------------------------------------------------------------
// k_fp3 (fp64, LDS doubles, 2-j/thread): t = relu(y3 + x2 @ w1[1024:] + b1);
// h2 = t @ w2 + b2. 8 points/block; j0 = tid&127 covers {j0, j0+128};
// pb = (tid>>7)*4 covers 4 points. grid 256.
__global__ void __launch_bounds__(256)
k_fp3(const float* __restrict__ x2, const double* __restrict__ y3p,
      const float* __restrict__ w1, const float* __restrict__ b1,
      const float* __restrict__ w2, const float* __restrict__ b2,
      float* __restrict__ h2) {
  __shared__ __align__(16) double rows[8][256];
  __shared__ __align__(16) double t[8][256];
  const int b = blockIdx.x >> 5;
  const int p0 = (blockIdx.x & 31) * 8;
  const int tid = threadIdx.x;
  const int j0 = tid & 127;
  const int pb = (tid >> 7) * 4;

  for (int p = 0; p < 8; ++p)
    rows[p][tid] = (double)x2[(((size_t)b * N2) + p0 + p) * 256 + tid];
  __syncthreads();

  {
    const double* yb = y3p + (size_t)b * 4 * 256;
    double acc[4][2];
    const double y0 = yb[j0] + yb[256 + j0] + yb[512 + j0] + yb[768 + j0];
    const double y1 = yb[j0 + 128] + yb[256 + j0 + 128] + yb[512 + j0 + 128] + yb[768 + j0 + 128];
#pragma unroll
    for (int p = 0; p < 4; ++p) { acc[p][0] = y0; acc[p][1] = y1; }
    const float* wj = w1 + (size_t)1024 * 256 + j0;
    for (int k4 = 0; k4 < 64; ++k4) {
      double wa[4], wb[4];
#pragma unroll
      for (int kk = 0; kk < 4; ++kk) {
        wa[kk] = (double)wj[(size_t)(4 * k4 + kk) * 256];
        wb[kk] = (double)wj[(size_t)(4 * k4 + kk) * 256 + 128];
      }
#pragma unroll
      for (int p = 0; p < 4; ++p) {
        const double* ip = &rows[pb + p][4 * k4];
        const double2 va = *(const double2*)(ip);
        const double2 vb = *(const double2*)(ip + 2);
        acc[p][0] += va.x * wa[0]; acc[p][1] += va.x * wb[0];
        acc[p][0] += va.y * wa[1]; acc[p][1] += va.y * wb[1];
        acc[p][0] += vb.x * wa[2]; acc[p][1] += vb.x * wb[2];
        acc[p][0] += vb.y * wa[3]; acc[p][1] += vb.y * wb[3];
      }
    }
    const double bb0 = (double)b1[j0], bb1 = (double)b1[j0 + 128];
#pragma unroll
    for (int p = 0; p < 4; ++p) {
      t[pb + p][j0] = fmax(acc[p][0] + bb0, 0.0);
      t[pb + p][j0 + 128] = fmax(acc[p][1] + bb1, 0.0);
    }
  }
  __syncthreads();
  {
    double acc[4][2];
    const double bb0 = (double)b2[j0], bb1 = (double)b2[j0 + 128];
#pragma unroll
    for (int p = 0; p < 4; ++p) { acc[p][0] = bb0; acc[p][1] = bb1; }
    const float* wj = w2 + j0;
    for (int k4 = 0; k4 < 64; ++k4) {
      double wa[4], wb[4];
#pragma unroll
      for (int kk = 0; kk < 4; ++kk) {
        wa[kk] = (double)wj[(size_t)(4 * k4 + kk) * 256];
        wb[kk] = (double)wj[(size_t)(4 * k4 + kk) * 256 + 128];
      }
#pragma unroll
      for (int p = 0; p < 4; ++p) {
        const double* ip = &t[pb + p][4 * k4];
        const double2 va = *(const double2*)(ip);
        const double2 vb = *(const double2*)(ip + 2);
        acc[p][0] += va.x * wa[0]; acc[p][1] += va.x * wb[0];
        acc[p][0] += va.y * wa[1]; acc[p][1] += va.y * wb[1];
        acc[p][0] += vb.x * wa[2]; acc[p][1] += vb.x * wb[2];
        acc[p][0] += vb.y * wa[3]; acc[p][1] += vb.y * wb[3];
      }
    }
#pragma unroll
    for (int p = 0; p < 4; ++p) {
      h2[(((size_t)b * N2) + p0 + pb + p) * 256 + j0] = (float)acc[p][0];
      h2[(((size_t)b * N2) + p0 + pb + p) * 256 + j0 + 128] = (float)acc[p][1];
    }
  }
}

// ---------------------------------------------------------------------------
// k_fp2 (fp64, LDS doubles, 2-j/thread): interp(h2,k=3)||x1 -> relu(384->256)
// -> 256->128. 8 points/block. grid 1024.
__global__ void __launch_bounds__(256)
k_fp2(const float* __restrict__ h2, const float* __restrict__ x1,
      const int* __restrict__ idx2, const double* __restrict__ wn2,
      const float* __restrict__ w1, const float* __restrict__ b1,
      const float* __restrict__ w2, const float* __restrict__ b2,
      float* __restrict__ h1) {
  __shared__ __align__(16) double rows[8][384];
  __shared__ __align__(16) double t[8][256];
  __shared__ int sidx[8][3];
  __shared__ double swn[8][3];
  const int b = blockIdx.x >> 7;
  const int p0 = (blockIdx.x & 127) * 8;
  const int tid = threadIdx.x;

  if (tid < 24) {
    const int p = tid / 3, i = tid % 3;
    const size_t g = ((size_t)b * N1 + p0 + p) * 3 + i;
    sidx[p][i] = idx2[g];
    swn[p][i] = wn2[g];
  }
  __syncthreads();

  {
    const float* base = h2 + (size_t)b * N2 * 256;
    for (int p = 0; p < 8; ++p) {
      rows[p][tid] = swn[p][0] * (double)base[(size_t)sidx[p][0] * 256 + tid] +
                     swn[p][1] * (double)base[(size_t)sidx[p][1] * 256 + tid] +
                     swn[p][2] * (double)base[(size_t)sidx[p][2] * 256 + tid];
    }
    if (tid < 128) {
      for (int p = 0; p < 8; ++p)
        rows[p][256 + tid] = (double)x1[((size_t)b * N1 + p0 + p) * 128 + tid];
    }
  }
  __syncthreads();

  {
    const int j0 = tid & 127;
    const int pb = (tid >> 7) * 4;
    double acc[4][2];
    const double bb0 = (double)b1[j0], bb1 = (double)b1[j0 + 128];
#pragma unroll
    for (int p = 0; p < 4; ++p) { acc[p][0] = bb0; acc[p][1] = bb1; }
    const float* wj = w1 + j0;
    for (int k4 = 0; k4 < 96; ++k4) {
      double wa[4], wb[4];
#pragma unroll
      for (int kk = 0; kk < 4; ++kk) {
        wa[kk] = (double)wj[(size_t)(4 * k4 + kk) * 256];
        wb[kk] = (double)wj[(size_t)(4 * k4 + kk) * 256 + 128];
      }
#pragma unroll
      for (int p = 0; p < 4; ++p) {
        const double* ip = &rows[pb + p][4 * k4];
        const double2 va = *(const double2*)(ip);
        const double2 vb = *(const double2*)(ip + 2);
        acc[p][0] += va.x * wa[0]; acc[p][1] += va.x * wb[0];
        acc[p][0] += va.y * wa[1]; acc[p][1] += va.y * wb[1];
        acc[p][0] += vb.x * wa[2]; acc[p][1] += vb.x * wb[2];
        acc[p][0] += vb.y * wa[3]; acc[p][1] += vb.y * wb[3];
      }
    }
#pragma unroll
    for (int p = 0; p < 4; ++p) {
      t[pb + p][j0] = fmax(acc[p][0], 0.0);
      t[pb + p][j0 + 128] = fmax(acc[p][1], 0.0);
    }
  }
  __syncthreads();

  {
    const int j0 = tid & 63;
    const int pb = ((tid >> 6) & 3) * 2;
    double acc[2][2];
    const double bb0 = (double)b2[j0], bb1 = (double)b2[j0 + 64];
#pragma unroll
    for (int p = 0; p < 2; ++p) { acc[p][0] = bb0; acc[p][1] = bb1; }
    const float* wj = w2 + j0;
    for (int k4 = 0; k4 < 64; ++k4) {
      double wa[4], wb[4];
#pragma unroll
      for (int kk = 0; kk < 4; ++kk) {
        wa[kk] = (double)wj[(size_t)(4 * k4 + kk) * 128];
        wb[kk] = (double)wj[(size_t)(4 * k4 + kk) * 128 + 64];
      }
#pragma unroll
      for (int p = 0; p < 2; ++p) {
        const double* ip = &t[pb + p][4 * k4];
        const double2 va = *(const double2*)(ip);
        const double2 vb = *(const double2*)(ip + 2);
        acc[p][0] += va.x * wa[0]; acc[p][1] += va.x * wb[0];
        acc[p][0] += va.y * wa[1]; acc[p][1] += va.y * wb[1];
        acc[p][0] += vb.x * wa[2]; acc[p][1] += vb.x * wb[2];
        acc[p][0] += vb.y * wa[3]; acc[p][1] += vb.y * wb[3];
      }
    }
#pragma unroll
    for (int p = 0; p < 2; ++p) {
      h1[((size_t)b * N1 + p0 + pb + p) * 128 + j0] = (float)acc[p][0];
      h1[((size_t)b * N1 + p0 + pb + p) * 128 + j0 + 64] = (float)acc[p][1];
    }
  }
}

// ---------------------------------------------------------------------------
// fp64 MLP layer on LDS doubles, 128-wide out: 16 points/block, 256 threads =
// 64 j-pairs x 4 point-groups of 4. Bias-first, k ascending (bit-stable).
template <int K, int INS, int OUTS, bool RELU>
__device__ __forceinline__ void mlpd(const double* __restrict__ in, double* __restrict__ out,
                                     const float* __restrict__ w,
                                     const float* __restrict__ bias, int tid) {
  constexpr int K4 = K / 4;
  const int j0 = tid & 63;
  const int pb = (tid >> 6) * 4;
  double acc[4][2];
  {
    const double b0 = (double)bias[j0], b1 = (double)bias[j0 + 64];
#pragma unroll
    for (int p = 0; p < 4; ++p) { acc[p][0] = b0; acc[p][1] = b1; }
  }
  const float* wj = w + j0;
  for (int k4 = 0; k4 < K4; ++k4) {
    double wa[4], wb[4];
#pragma unroll
    for (int kk = 0; kk < 4; ++kk) {
      wa[kk] = (double)wj[(size_t)(4 * k4 + kk) * 128];
      wb[kk] = (double)wj[(size_t)(4 * k4 + kk) * 128 + 64];
    }
#pragma unroll
    for (int p = 0; p < 4; ++p) {
      const double* ip = in + (pb + p) * INS + 4 * k4;
      const double2 va = *(const double2*)(ip);
      const double2 vb = *(const double2*)(ip + 2);
      acc[p][0] += va.x * wa[0]; acc[p][1] += va.x * wb[0];
      acc[p][0] += va.y * wa[1]; acc[p][1] += va.y * wb[1];
      acc[p][0] += vb.x * wa[2]; acc[p][1] += vb.x * wb[2];
      acc[p][0] += vb.y * wa[3]; acc[p][1] += vb.y * wb[3];
    }
  }
#pragma unroll
  for (int k = K4 * 4; k < K; ++k) {
    const double wa = (double)wj[(size_t)k * 128];
    const double wb = (double)wj[(size_t)k * 128 + 64];
#pragma unroll
    for (int p = 0; p < 4; ++p) {
      const double v = in[(pb + p) * INS + k];
      acc[p][0] += v * wa; acc[p][1] += v * wb;
    }
  }
#pragma unroll
  for (int p = 0; p < 4; ++p) {
    const double v0 = acc[p][0], v1 = acc[p][1];
    out[(pb + p) * OUTS + j0] = RELU ? fmax(v0, 0.0) : v0;
    out[(pb + p) * OUTS + j0 + 64] = RELU ? fmax(v1, 0.0) : v1;
  }
}

// k_fp1head: interp(h1)||pos0 -> [131->128 r] -> [128 r] -> [128] -> cat af ->
//            [160->128 r] -> [128 r] -> [128->1]  (all fp64; LDS doubles)
__global__ void __launch_bounds__(256)
k_fp1head(const float* __restrict__ h1, const float* __restrict__ pos0,
          const int* __restrict__ idx1, const double* __restrict__ wn1,
          const float* __restrict__ afv,
          const float* __restrict__ w1, const float* __restrict__ b1,
          const float* __restrict__ w2, const float* __restrict__ b2,
          const float* __restrict__ w3, const float* __restrict__ b3,
          const float* __restrict__ hw1, const float* __restrict__ hb1,
          const float* __restrict__ hw2, const float* __restrict__ hb2,
          const float* __restrict__ hw3, const float* __restrict__ hb3,
          float* __restrict__ out) {
  __shared__ __align__(16) double A[16][132];
  __shared__ __align__(16) double Bf[16][160];
  __shared__ int sidx[16][3];
  __shared__ double swn[16][3];
  __shared__ double af_s[32];
  const int b = blockIdx.x >> 8;
  const int p0 = (blockIdx.x & 255) * 16;
  const int tid = threadIdx.x;

  if (tid < 48) {
    const int p = tid / 3, i = tid % 3;
    const size_t g = ((size_t)b * N0 + p0 + p) * 3 + i;
    sidx[p][i] = idx1[g];
    swn[p][i] = wn1[g];
  }
  if (tid >= 64 && tid < 96) af_s[tid - 64] = (double)afv[b * 32 + (tid - 64)];
  __syncthreads();

  {
    const int c = tid & 127;
    const float* base = h1 + (size_t)b * N1 * 128;
    for (int p = (tid >> 7); p < 16; p += 2) {
      A[p][c] = swn[p][0] * (double)base[(size_t)sidx[p][0] * 128 + c] +
                swn[p][1] * (double)base[(size_t)sidx[p][1] * 128 + c] +
                swn[p][2] * (double)base[(size_t)sidx[p][2] * 128 + c];
    }
  }
  if (tid < 48) {
    const int p = tid / 3, i = tid % 3;
    A[p][128 + i] = (double)pos0[((size_t)b * N0 + p0 + p) * 3 + i];
  }
  __syncthreads();

  mlpd<131, 132, 160, true>(&A[0][0], &Bf[0][0], w1, b1, tid);
  __syncthreads();
  mlpd<128, 160, 132, true>(&Bf[0][0], &A[0][0], w2, b2, tid);
  __syncthreads();
  mlpd<128, 132, 160, false>(&A[0][0], &Bf[0][0], w3, b3, tid);
  for (int x = tid; x < 16 * 32; x += 256)
    Bf[x >> 5][128 + (x & 31)] = af_s[x & 31];
  __syncthreads();
  mlpd<160, 160, 132, true>(&Bf[0][0], &A[0][0], hw1, hb1, tid);
  __syncthreads();
  mlpd<128, 132, 160, true>(&A[0][0], &Bf[0][0], hw2, hb2, tid);
  __syncthreads();

  // head3: fp64 dot, 16 lanes per point
  {
    const int p = tid >> 4, l = tid & 15;
    double acc = 0.0;
    for (int k = l; k < 128; k += 16)
      acc += Bf[p][k] * (double)hw3[k];
    for (int off = 8; off > 0; off >>= 1)
      acc += __shfl_down(acc, off, 16);
    if (l == 0)
      out[(size_t)b * N0 + p0 + p] = (float)(acc + (double)hb3[0]);
  }
}

// ---------------------------------------------------------------------------
extern "C" void kernel_launch(void* const* d_in, const int* in_sizes, int n_in,
                              void* d_out, int out_size, void* d_ws, size_t ws_size,
                              hipStream_t stream) {
  const float* pos0 = (const float*)d_in[0];
  const float* x1   = (const float*)d_in[1];
  const float* pos1 = (const float*)d_in[2];
  const float* x2   = (const float*)d_in[3];
  const float* pos2 = (const float*)d_in[4];
  const float* x3   = (const float*)d_in[5];
  /* d_in[6] = pos3: unused (k=1 interp from a single point is a broadcast) */
  const float* ap   = (const float*)d_in[7];
  const float* fp3w1 = (const float*)d_in[8];
  const float* fp3b1 = (const float*)d_in[9];
  const float* fp3w2 = (const float*)d_in[10];
  const float* fp3b2 = (const float*)d_in[11];
  const float* fp2w1 = (const float*)d_in[12];
  const float* fp2b1 = (const float*)d_in[13];
  const float* fp2w2 = (const float*)d_in[14];
  const float* fp2b2 = (const float*)d_in[15];
  const float* fp1w1 = (const float*)d_in[16];
  const float* fp1b1 = (const float*)d_in[17];
  const float* fp1w2 = (const float*)d_in[18];
  const float* fp1b2 = (const float*)d_in[19];
  const float* fp1w3 = (const float*)d_in[20];
  const float* fp1b3 = (const float*)d_in[21];
  const float* encw1 = (const float*)d_in[22];
  const float* encb1 = (const float*)d_in[23];
  const float* encw2 = (const float*)d_in[24];
  const float* encb2 = (const float*)d_in[25];
  const float* hw1 = (const float*)d_in[26];
  const float* hb1 = (const float*)d_in[27];
  const float* hw2 = (const float*)d_in[28];
  const float* hb2 = (const float*)d_in[29];
  const float* hw3 = (const float*)d_in[30];
  const float* hb3 = (const float*)d_in[31];
  float* out = (float*)d_out;

  // Alias-free layout; total 7,832,576 B (== round-1/3's proven footprint).
  char* p = (char*)d_ws;
  double* y3p = (double*)p; p += (size_t)BB * 4 * 256 * 8;   // 64 KB
  double* wn2 = (double*)p; p += (size_t)BB * N1 * 3 * 8;    // 192 KB
  double* wn1 = (double*)p; p += (size_t)BB * N0 * 3 * 8;    // 768 KB
  float*  af  = (float*)p;  p += (size_t)BB * 32 * 4;        // 1 KB
  int*    idx2= (int*)p;    p += (size_t)BB * N1 * 3 * 4;    // 96 KB
  int*    idx1= (int*)p;    p += (size_t)BB * N0 * 3 * 4;    // 384 KB
  float*  h2  = (float*)p;  p += (size_t)BB * N2 * 256 * 4;  // 2 MB
  float*  h1  = (float*)p;  p += (size_t)BB * N1 * 128 * 4;  // 4 MB

  hipLaunchKernelGGL(k_y3_enc, dim3(BB, 4), dim3(256), 0, stream,
                     x3, fp3w1, y3p, ap, encw1, encb1, encw2, encb2, af);
  hipLaunchKernelGGL((k_knn4<N2, N1>), dim3(BB * (N1 / 64)), dim3(256), 0, stream,
                     pos2, pos1, idx2, wn2);
  hipLaunchKernelGGL((k_knn4<N1, N0>), dim3(BB * (N0 / 64)), dim3(256), 0, stream,
                     pos1, pos0, idx1, wn1);
  hipLaunchKernelGGL(k_fp3, dim3(BB * N2 / 8), dim3(256), 0, stream,
                     x2, y3p, fp3w1, fp3b1, fp3w2, fp3b2, h2);
  hipLaunchKernelGGL(k_fp2, dim3(BB * N1 / 8), dim3(256), 0, stream,
                     h2, x1, idx2, wn2, fp2w1, fp2b1, fp2w2, fp2b2, h1);
  hipLaunchKernelGGL(k_fp1head, dim3(BB * N0 / 16), dim3(256), 0, stream,
                     h1, pos0, idx1, wn1, af,
                     fp1w1, fp1b1, fp1w2, fp1b2, fp1w3, fp1b3,
                     hw1, hb1, hw2, hb2, hw3, hb3, out);
}

// Round 7
// 395.884 us; speedup vs baseline: 1.5107x; 1.0700x over previous
//
#include <hip/hip_runtime.h>

// Sizes (fixed by the problem)
#define BB   8
#define N0   4096
#define N1   1024
#define N2   256
#define GG   1024
#define AFW  32

typedef unsigned long long u64;
typedef double d4 __attribute__((ext_vector_type(4)));

// ---------------------------------------------------------------------------
// Branchless top-3 insert on u64 keys (distance bits | index), stable.
__device__ __forceinline__ void ins3(u64 key, u64& k0, u64& k1, u64& k2) {
  const bool c0 = key < k0, c1 = key < k1, c2 = key < k2;
  const u64 n2 = c1 ? k1 : (c2 ? key : k2);
  const u64 n1 = c0 ? k0 : (c1 ? key : k1);
  k0 = c0 ? key : k0; k1 = n1; k2 = n2;
}

// ---------------------------------------------------------------------------
// k_probe: decode the f64 MFMA C/D (lane,reg)->(row,col) mapping on-device.
// P1: A[i][k] = (k-slot0 ? i+1 : 0), B = 1  => D[i][j] = i+1 (decodes row)
// P2: A = 1, B[k][j] = (k-slot0 ? j+1 : 0)  => D[i][j] = j+1 (decodes col)
// Self-consistent for ANY fixed lane-permutation layouts, because the MLP
// kernels load A/B with the same slot conventions (m = lane&15, g = lane>>4).
__global__ void __launch_bounds__(64)
k_probe(int* __restrict__ tab) {
  const int lane = threadIdx.x;
  const int m = lane & 15, g = lane >> 4;
  const d4 z = {0.0, 0.0, 0.0, 0.0};
  const double e = (g == 0) ? (double)(m + 1) : 0.0;
  d4 r1 = __builtin_amdgcn_mfma_f64_16x16x4f64(e, 1.0, z, 0, 0, 0);
  d4 r2 = __builtin_amdgcn_mfma_f64_16x16x4f64(1.0, e, z, 0, 0, 0);
#pragma unroll
  for (int r = 0; r < 4; ++r) {
    const int row = ((int)r1[r] - 1) & 15;
    const int col = ((int)r2[r] - 1) & 15;
    tab[lane * 4 + r] = (row << 8) | col;
  }
}

// ---------------------------------------------------------------------------
// k_y3_enc: y3 partials (x3 @ fp3_w1[:1024,:]) split over 4 K-chunks (fp64),
// plus the approach-point encoder folded into part==0 blocks. grid (8,4) x 256
__global__ void __launch_bounds__(256)
k_y3_enc(const float* __restrict__ x3, const float* __restrict__ w1,
         double* __restrict__ y3p,
         const float* __restrict__ ap,
         const float* __restrict__ ew1, const float* __restrict__ eb1,
         const float* __restrict__ ew2, const float* __restrict__ eb2,
         float* __restrict__ af) {
  __shared__ double hs[32];
  const int b = blockIdx.x, part = blockIdx.y, tid = threadIdx.x;
  double acc = 0.0;
  const float* xr = x3 + (size_t)b * GG + part * 256;
  const float* wr = w1 + (size_t)part * 256 * 256;
  for (int k = 0; k < 256; ++k)
    acc += (double)xr[k] * (double)wr[k * 256 + tid];
  y3p[((size_t)b * 4 + part) * 256 + tid] = acc;

  if (part == 0) {
    if (tid < 32) {
      double a = (double)eb1[tid];
      for (int k = 0; k < 3; ++k)
        a += (double)ap[b * 3 + k] * (double)ew1[k * 32 + tid];
      hs[tid] = fmax(a, 0.0);
    }
    __syncthreads();
    if (tid < 32) {
      double a = (double)eb2[tid];
      for (int k = 0; k < 32; ++k)
        a += hs[k] * (double)ew2[k * 32 + tid];
      af[b * 32 + tid] = (float)a;
    }
  }
}

// ---------------------------------------------------------------------------
// 4-wave-split branchless 3-NN (unchanged; verified rounds 4/5-init).
template <int NCAND, int QTOT>
__global__ void __launch_bounds__(256)
k_knn4(const float* __restrict__ cpos, const float* __restrict__ qpos,
       int* __restrict__ idxo, double* __restrict__ wno) {
  __shared__ double ps[NCAND * 3];
  __shared__ u64 topw[4][64][3];
  const int qc = blockIdx.x % (QTOT / 64);
  const int b = blockIdx.x / (QTOT / 64);
  const int tid = threadIdx.x;
  {
    const float* src = cpos + (size_t)b * NCAND * 3;
    for (int i = tid; i < NCAND * 3; i += 256) ps[i] = (double)src[i];
  }
  __syncthreads();

  const int wave = tid >> 6, lane = tid & 63;
  const size_t gq = (size_t)b * QTOT + qc * 64 + lane;
  const double qx = (double)qpos[gq * 3 + 0];
  const double qy = (double)qpos[gq * 3 + 1];
  const double qz = (double)qpos[gq * 3 + 2];

  constexpr int NC4 = NCAND / 4;
  u64 k0 = ~0ull, k1 = ~0ull, k2 = ~0ull;
  const int kbeg = wave * NC4;
#pragma unroll 2
  for (int kk = 0; kk < NC4; ++kk) {
    const int k = kbeg + kk;
    const double dx = qx - ps[3 * k + 0];
    const double dy = qy - ps[3 * k + 1];
    const double dz = qz - ps[3 * k + 2];
    const double d = dx * dx + dy * dy + dz * dz;
    const u64 key = (((u64)__double_as_longlong(d)) & ~1023ull) | (unsigned)k;
    ins3(key, k0, k1, k2);
  }
  topw[wave][lane][0] = k0; topw[wave][lane][1] = k1; topw[wave][lane][2] = k2;
  __syncthreads();

  if (tid < 64) {
    u64 m0 = ~0ull, m1 = ~0ull, m2 = ~0ull;
#pragma unroll
    for (int w = 0; w < 4; ++w)
#pragma unroll
      for (int s = 0; s < 3; ++s)
        ins3(topw[w][tid][s], m0, m1, m2);
    const double d0 = __longlong_as_double((long long)(m0 & ~1023ull));
    const double d1 = __longlong_as_double((long long)(m1 & ~1023ull));
    const double d2 = __longlong_as_double((long long)(m2 & ~1023ull));
    const double w0 = 1.0 / fmax(d0, 1e-16);
    const double w1 = 1.0 / fmax(d1, 1e-16);
    const double w2 = 1.0 / fmax(d2, 1e-16);
    const double inv = 1.0 / (w0 + w1 + w2);
    const size_t go = (size_t)b * QTOT + qc * 64 + tid;
    idxo[go * 3 + 0] = (int)(m0 & 1023ull);
    idxo[go * 3 + 1] = (int)(m1 & 1023ull);
    idxo[go * 3 + 2] = (int)(m2 & 1023ull);
    wno[go * 3 + 0] = w0 * inv;
    wno[go * 3 + 1] = w1 * inv;
    wno[go * 3 + 2] = w2 * inv;
  }
}

// ---------------------------------------------------------------------------
// fp64-MFMA MLP layer, layout-adaptive via probe table rc4 (per-lane 4 packed
// (row<<8)|col entries). Block = 4 waves x 16 points; wave wv owns j-tiles
// [wv*NT*16, (wv+1)*NT*16). A slot: a = act[point=m][k=4s+g]; B slot:
// bv = w[k=4s+g][j = jb+t*16+m]; D slot r maps to (rw[r], cl[r]) within tile.
// K%4 tail: LDS cols K.. zero-padded; weight load predicated (no OOB).
template <int NT, int K, int INS_S, int OUTS_S, bool RELU, bool Y3>
__device__ __forceinline__ void
mfma_layer(const float* __restrict__ inL, float* __restrict__ outP,
           const float* __restrict__ w, const float* __restrict__ bias,
           const double* __restrict__ y3b, int lane, int wv, int4 rc4) {
  const int m = lane & 15, g = lane >> 4;
  const int jb = wv * (NT * 16);
  constexpr int JT = NT * 64;
  int rw[4], cl[4];
  rw[0] = (rc4.x >> 8) & 15; cl[0] = rc4.x & 15;
  rw[1] = (rc4.y >> 8) & 15; cl[1] = rc4.y & 15;
  rw[2] = (rc4.z >> 8) & 15; cl[2] = rc4.z & 15;
  rw[3] = (rc4.w >> 8) & 15; cl[3] = rc4.w & 15;
  d4 acc[NT];
#pragma unroll
  for (int t = 0; t < NT; ++t) {
#pragma unroll
    for (int r = 0; r < 4; ++r) {
      const int j = jb + t * 16 + cl[r];
      double base = (double)bias[j];
      if (Y3) base += y3b[j] + y3b[256 + j] + y3b[512 + j] + y3b[768 + j];
      acc[t][r] = base;
    }
  }
  constexpr int FULL = K / 4;
#pragma unroll 2
  for (int s = 0; s < FULL; ++s) {
    const double a = (double)inL[m * INS_S + 4 * s + g];
    const float* wr = w + (size_t)(4 * s + g) * JT + jb + m;
#pragma unroll
    for (int t = 0; t < NT; ++t) {
      const double bv = (double)wr[t * 16];
      acc[t] = __builtin_amdgcn_mfma_f64_16x16x4f64(a, bv, acc[t], 0, 0, 0);
    }
  }
  if constexpr ((K & 3) != 0) {
    const int kk = FULL * 4 + g;
    const double a = (double)inL[m * INS_S + kk];  // zero-padded past K
    const bool ok = kk < K;
    const float* wr = w + (size_t)kk * JT + jb + m;
#pragma unroll
    for (int t = 0; t < NT; ++t) {
      double bv = 0.0;
      if (ok) bv = (double)wr[t * 16];
      acc[t] = __builtin_amdgcn_mfma_f64_16x16x4f64(a, bv, acc[t], 0, 0, 0);
    }
  }
#pragma unroll
  for (int t = 0; t < NT; ++t)
#pragma unroll
    for (int r = 0; r < 4; ++r) {
      float v = (float)acc[t][r];
      if (RELU) v = fmaxf(v, 0.f);
      outP[(size_t)rw[r] * OUTS_S + jb + t * 16 + cl[r]] = v;
    }
}

// ---------------------------------------------------------------------------
// k_fp3: 16 points/block, grid 128. t = relu(y3 + x2 @ w1[1024:] + b1);
// h2 = t @ w2 + b2 (straight to global).
__global__ void __launch_bounds__(256)
k_fp3(const float* __restrict__ x2, const double* __restrict__ y3p,
      const float* __restrict__ w1, const float* __restrict__ b1,
      const float* __restrict__ w2, const float* __restrict__ b2,
      float* __restrict__ h2, const int* __restrict__ mtab) {
  __shared__ float rows[16 * 261];
  __shared__ float t[16 * 261];
  const int b = blockIdx.x >> 4;
  const int p0 = (blockIdx.x & 15) * 16;
  const int tid = threadIdx.x;
  const int lane = tid & 63, wv = tid >> 6;
  const int4 rc4 = *(const int4*)(mtab + lane * 4);
  for (int p = 0; p < 16; ++p)
    rows[p * 261 + tid] = x2[((size_t)b * N2 + p0 + p) * 256 + tid];
  __syncthreads();
  mfma_layer<4, 256, 261, 261, true, true>(rows, t, w1 + (size_t)1024 * 256, b1,
                                           y3p + (size_t)b * 1024, lane, wv, rc4);
  __syncthreads();
  mfma_layer<4, 256, 261, 256, false, false>(t, h2 + ((size_t)b * N2 + p0) * 256,
                                             w2, b2, nullptr, lane, wv, rc4);
}

// ---------------------------------------------------------------------------
// k_fp2: 16 points/block, grid 512. interp(h2,k=3)||x1 -> relu(384->256)
// -> 256->128 (straight to global h1).
__global__ void __launch_bounds__(256)
k_fp2(const float* __restrict__ h2, const float* __restrict__ x1,
      const int* __restrict__ idx2, const double* __restrict__ wn2,
      const float* __restrict__ w1, const float* __restrict__ b1,
      const float* __restrict__ w2, const float* __restrict__ b2,
      float* __restrict__ h1, const int* __restrict__ mtab) {
  __shared__ float rows[16 * 389];
  __shared__ float t[16 * 261];
  __shared__ int sidx[16][3];
  __shared__ double swn[16][3];
  const int b = blockIdx.x >> 6;
  const int p0 = (blockIdx.x & 63) * 16;
  const int tid = threadIdx.x;
  const int lane = tid & 63, wv = tid >> 6;
  const int4 rc4 = *(const int4*)(mtab + lane * 4);

  if (tid < 48) {
    const int p = tid / 3, i = tid % 3;
    const size_t g = ((size_t)b * N1 + p0 + p) * 3 + i;
    sidx[p][i] = idx2[g];
    swn[p][i] = wn2[g];
  }
  __syncthreads();

  {
    const float* base = h2 + (size_t)b * N2 * 256;
    for (int p = 0; p < 16; ++p) {
      const double v = swn[p][0] * (double)base[(size_t)sidx[p][0] * 256 + tid] +
                       swn[p][1] * (double)base[(size_t)sidx[p][1] * 256 + tid] +
                       swn[p][2] * (double)base[(size_t)sidx[p][2] * 256 + tid];
      rows[p * 389 + tid] = (float)v;
    }
    for (int i = 0; i < 8; ++i) {
      const int p = i * 2 + (tid >> 7), c = tid & 127;
      rows[p * 389 + 256 + c] = x1[((size_t)b * N1 + p0 + p) * 128 + c];
    }
  }
  __syncthreads();
  mfma_layer<4, 384, 389, 261, true, false>(rows, t, w1, b1, nullptr, lane, wv, rc4);
  __syncthreads();
  mfma_layer<2, 256, 261, 128, false, false>(t, h1 + ((size_t)b * N1 + p0) * 128,
                                             w2, b2, nullptr, lane, wv, rc4);
}

// ---------------------------------------------------------------------------
// k_fp1head: 16 points/block, grid 2048. interp(h1)||pos0 -> [131->128 r] ->
// [128 r] -> [128] -> cat af -> [160->128 r] -> [128 r] -> [128->1].
__global__ void __launch_bounds__(256)
k_fp1head(const float* __restrict__ h1, const float* __restrict__ pos0,
          const int* __restrict__ idx1, const double* __restrict__ wn1,
          const float* __restrict__ afv,
          const float* __restrict__ w1, const float* __restrict__ b1,
          const float* __restrict__ w2, const float* __restrict__ b2,
          const float* __restrict__ w3, const float* __restrict__ b3,
          const float* __restrict__ hw1, const float* __restrict__ hb1,
          const float* __restrict__ hw2, const float* __restrict__ hb2,
          const float* __restrict__ hw3, const float* __restrict__ hb3,
          float* __restrict__ out, const int* __restrict__ mtab) {
  __shared__ float A[16 * 137];   // inputs 131 (+zero pad); also L2/L4 outputs
  __shared__ float Bf[16 * 165];  // L1/L3/L5 outputs; cols 128..159 = af
  __shared__ int sidx[16][3];
  __shared__ double swn[16][3];
  const int b = blockIdx.x >> 8;
  const int p0 = (blockIdx.x & 255) * 16;
  const int tid = threadIdx.x;
  const int lane = tid & 63, wv = tid >> 6;
  const int4 rc4 = *(const int4*)(mtab + lane * 4);

  if (tid < 48) {
    const int p = tid / 3, i = tid % 3;
    const size_t g = ((size_t)b * N0 + p0 + p) * 3 + i;
    sidx[p][i] = idx1[g];
    swn[p][i] = wn1[g];
  }
  if (tid >= 64 && tid < 80) {       // zero-pad A cols 131..136 (L1 K-tail)
    const int p = tid - 64;
    for (int c = 131; c < 137; ++c) A[p * 137 + c] = 0.f;
  }
  for (int x = tid; x < 512; x += 256)  // af -> Bf cols 128..159 (survive L1/L3)
    Bf[(x >> 5) * 165 + 128 + (x & 31)] = afv[b * 32 + (x & 31)];
  __syncthreads();

  {
    const int c = tid & 127;
    const float* basep = h1 + (size_t)b * N1 * 128;
    for (int p = (tid >> 7); p < 16; p += 2) {
      const double v = swn[p][0] * (double)basep[(size_t)sidx[p][0] * 128 + c] +
                       swn[p][1] * (double)basep[(size_t)sidx[p][1] * 128 + c] +
                       swn[p][2] * (double)basep[(size_t)sidx[p][2] * 128 + c];
      A[p * 137 + c] = (float)v;
    }
  }
  if (tid < 48) {
    const int p = tid / 3, i = tid % 3;
    A[p * 137 + 128 + i] = pos0[((size_t)b * N0 + p0 + p) * 3 + i];
  }
  __syncthreads();

  mfma_layer<2, 131, 137, 165, true,  false>(A,  Bf, w1,  b1,  nullptr, lane, wv, rc4);
  __syncthreads();
  mfma_layer<2, 128, 165, 137, true,  false>(Bf, A,  w2,  b2,  nullptr, lane, wv, rc4);
  __syncthreads();
  mfma_layer<2, 128, 137, 165, false, false>(A,  Bf, w3,  b3,  nullptr, lane, wv, rc4);
  __syncthreads();
  mfma_layer<2, 160, 165, 137, true,  false>(Bf, A,  hw1, hb1, nullptr, lane, wv, rc4);
  __syncthreads();
  mfma_layer<2, 128, 137, 165, true,  false>(A,  Bf, hw2, hb2, nullptr, lane, wv, rc4);
  __syncthreads();

  // head3: fp64 dot, 16 lanes per point
  {
    const int p = tid >> 4, l = tid & 15;
    double acc = 0.0;
    for (int k = l; k < 128; k += 16)
      acc += (double)Bf[p * 165 + k] * (double)hw3[k];
    for (int off = 8; off > 0; off >>= 1)
      acc += __shfl_down(acc, off, 16);
    if (l == 0)
      out[(size_t)b * N0 + p0 + p] = (float)(acc + (double)hb3[0]);
  }
}

// ---------------------------------------------------------------------------
extern "C" void kernel_launch(void* const* d_in, const int* in_sizes, int n_in,
                              void* d_out, int out_size, void* d_ws, size_t ws_size,
                              hipStream_t stream) {
  const float* pos0 = (const float*)d_in[0];
  const float* x1   = (const float*)d_in[1];
  const float* pos1 = (const float*)d_in[2];
  const float* x2   = (const float*)d_in[3];
  const float* pos2 = (const float*)d_in[4];
  const float* x3   = (const float*)d_in[5];
  /* d_in[6] = pos3: unused (k=1 interp from a single point is a broadcast) */
  const float* ap   = (const float*)d_in[7];
  const float* fp3w1 = (const float*)d_in[8];
  const float* fp3b1 = (const float*)d_in[9];
  const float* fp3w2 = (const float*)d_in[10];
  const float* fp3b2 = (const float*)d_in[11];
  const float* fp2w1 = (const float*)d_in[12];
  const float* fp2b1 = (const float*)d_in[13];
  const float* fp2w2 = (const float*)d_in[14];
  const float* fp2b2 = (const float*)d_in[15];
  const float* fp1w1 = (const float*)d_in[16];
  const float* fp1b1 = (const float*)d_in[17];
  const float* fp1w2 = (const float*)d_in[18];
  const float* fp1b2 = (const float*)d_in[19];
  const float* fp1w3 = (const float*)d_in[20];
  const float* fp1b3 = (const float*)d_in[21];
  const float* encw1 = (const float*)d_in[22];
  const float* encb1 = (const float*)d_in[23];
  const float* encw2 = (const float*)d_in[24];
  const float* encb2 = (const float*)d_in[25];
  const float* hw1 = (const float*)d_in[26];
  const float* hb1 = (const float*)d_in[27];
  const float* hw2 = (const float*)d_in[28];
  const float* hb2 = (const float*)d_in[29];
  const float* hw3 = (const float*)d_in[30];
  const float* hb3 = (const float*)d_in[31];
  float* out = (float*)d_out;

  // Alias-free layout (+1 KB probe table).
  char* p = (char*)d_ws;
  double* y3p = (double*)p; p += (size_t)BB * 4 * 256 * 8;   // 64 KB
  double* wn2 = (double*)p; p += (size_t)BB * N1 * 3 * 8;    // 192 KB
  double* wn1 = (double*)p; p += (size_t)BB * N0 * 3 * 8;    // 768 KB
  float*  af  = (float*)p;  p += (size_t)BB * 32 * 4;        // 1 KB
  int*    idx2= (int*)p;    p += (size_t)BB * N1 * 3 * 4;    // 96 KB
  int*    idx1= (int*)p;    p += (size_t)BB * N0 * 3 * 4;    // 384 KB
  float*  h2  = (float*)p;  p += (size_t)BB * N2 * 256 * 4;  // 2 MB
  float*  h1  = (float*)p;  p += (size_t)BB * N1 * 128 * 4;  // 4 MB
  int*    mtab= (int*)p;    p += 1024;                        // 64 lanes x 4

  hipLaunchKernelGGL(k_probe, dim3(1), dim3(64), 0, stream, mtab);
  hipLaunchKernelGGL(k_y3_enc, dim3(BB, 4), dim3(256), 0, stream,
                     x3, fp3w1, y3p, ap, encw1, encb1, encw2, encb2, af);
  hipLaunchKernelGGL((k_knn4<N2, N1>), dim3(BB * (N1 / 64)), dim3(256), 0, stream,
                     pos2, pos1, idx2, wn2);
  hipLaunchKernelGGL((k_knn4<N1, N0>), dim3(BB * (N0 / 64)), dim3(256), 0, stream,
                     pos1, pos0, idx1, wn1);
  hipLaunchKernelGGL(k_fp3, dim3(BB * N2 / 16), dim3(256), 0, stream,
                     x2, y3p, fp3w1, fp3b1, fp3w2, fp3b2, h2, mtab);
  hipLaunchKernelGGL(k_fp2, dim3(BB * N1 / 16), dim3(256), 0, stream,
                     h2, x1, idx2, wn2, fp2w1, fp2b1, fp2w2, fp2b2, h1, mtab);
  hipLaunchKernelGGL(k_fp1head, dim3(BB * N0 / 16), dim3(256), 0, stream,
                     h1, pos0, idx1, wn1, af,
                     fp1w1, fp1b1, fp1w2, fp1b2, fp1w3, fp1b3,
                     hw1, hb1, hw2, hb2, hw3, hb3, out, mtab);
}

// Round 9
// 328.286 us; speedup vs baseline: 1.8217x; 1.2059x over previous
//
#include <hip/hip_runtime.h>

// Sizes (fixed by the problem)
#define BB   8
#define N0   4096
#define N1   1024
#define N2   256
#define GG   1024
#define AFW  32

typedef unsigned long long u64;
typedef double d4 __attribute__((ext_vector_type(4)));

// ---------------------------------------------------------------------------
// Branchless top-3 insert on u64 keys (distance bits | index), stable.
__device__ __forceinline__ void ins3(u64 key, u64& k0, u64& k1, u64& k2) {
  const bool c0 = key < k0, c1 = key < k1, c2 = key < k2;
  const u64 n2 = c1 ? k1 : (c2 ? key : k2);
  const u64 n1 = c0 ? k0 : (c1 ? key : k1);
  k0 = c0 ? key : k0; k1 = n1; k2 = n2;
}

// ---------------------------------------------------------------------------
// knn body: 64 queries x 4 candidate-quarter waves, LDS merge (order-free:
// keys unique). Keys = fp64 d2 bits, low 10 mantissa bits = candidate index.
template <int NCAND, int QTOT>
__device__ __forceinline__ void
knn_body(int idx, const float* __restrict__ cpos, const float* __restrict__ qpos,
         int* __restrict__ idxo, double* __restrict__ wno,
         double* __restrict__ ps, u64* __restrict__ topw) {
  const int qc = idx % (QTOT / 64);
  const int b = idx / (QTOT / 64);
  const int tid = threadIdx.x;
  {
    const float* src = cpos + (size_t)b * NCAND * 3;
    for (int i = tid; i < NCAND * 3; i += 256) ps[i] = (double)src[i];
  }
  __syncthreads();

  const int wave = tid >> 6, lane = tid & 63;
  const size_t gq = (size_t)b * QTOT + qc * 64 + lane;
  const double qx = (double)qpos[gq * 3 + 0];
  const double qy = (double)qpos[gq * 3 + 1];
  const double qz = (double)qpos[gq * 3 + 2];

  constexpr int NC4 = NCAND / 4;
  u64 k0 = ~0ull, k1 = ~0ull, k2 = ~0ull;
  const int kbeg = wave * NC4;
#pragma unroll 2
  for (int kk = 0; kk < NC4; ++kk) {
    const int k = kbeg + kk;
    const double dx = qx - ps[3 * k + 0];
    const double dy = qy - ps[3 * k + 1];
    const double dz = qz - ps[3 * k + 2];
    const double d = dx * dx + dy * dy + dz * dz;
    const u64 key = (((u64)__double_as_longlong(d)) & ~1023ull) | (unsigned)k;
    ins3(key, k0, k1, k2);
  }
  topw[(wave * 64 + lane) * 3 + 0] = k0;
  topw[(wave * 64 + lane) * 3 + 1] = k1;
  topw[(wave * 64 + lane) * 3 + 2] = k2;
  __syncthreads();

  if (tid < 64) {
    u64 m0 = ~0ull, m1 = ~0ull, m2 = ~0ull;
#pragma unroll
    for (int w = 0; w < 4; ++w)
#pragma unroll
      for (int s = 0; s < 3; ++s)
        ins3(topw[(w * 64 + tid) * 3 + s], m0, m1, m2);
    const double d0 = __longlong_as_double((long long)(m0 & ~1023ull));
    const double d1 = __longlong_as_double((long long)(m1 & ~1023ull));
    const double d2 = __longlong_as_double((long long)(m2 & ~1023ull));
    const double w0 = 1.0 / fmax(d0, 1e-16);
    const double w1 = 1.0 / fmax(d1, 1e-16);
    const double w2 = 1.0 / fmax(d2, 1e-16);
    const double inv = 1.0 / (w0 + w1 + w2);
    const size_t go = (size_t)b * QTOT + qc * 64 + tid;
    idxo[go * 3 + 0] = (int)(m0 & 1023ull);
    idxo[go * 3 + 1] = (int)(m1 & 1023ull);
    idxo[go * 3 + 2] = (int)(m2 & 1023ull);
    wno[go * 3 + 0] = w0 * inv;
    wno[go * 3 + 1] = w1 * inv;
    wno[go * 3 + 2] = w2 * inv;
  }
}

// ---------------------------------------------------------------------------
// k_setup: fused {probe | y3_enc | knn2 | knn1} via blockIdx ranges.
//   block 0       : f64-MFMA C/D layout probe -> mtab
//   blocks 1..32  : y3 partials (x3 @ fp3_w1[:1024]) + approach encoder
//   blocks 33..160: knn2 (1024 queries vs 256 cands), 128 blocks
//   blocks 161..672: knn1 (4096 queries vs 1024 cands), 512 blocks
__global__ void __launch_bounds__(256)
k_setup(const float* __restrict__ pos0, const float* __restrict__ pos1,
        const float* __restrict__ pos2,
        const float* __restrict__ x3, const float* __restrict__ w1,
        double* __restrict__ y3p,
        const float* __restrict__ ap,
        const float* __restrict__ ew1, const float* __restrict__ eb1,
        const float* __restrict__ ew2, const float* __restrict__ eb2,
        float* __restrict__ af,
        int* __restrict__ idx2, double* __restrict__ wn2,
        int* __restrict__ idx1, double* __restrict__ wn1,
        int* __restrict__ mtab) {
  __shared__ double ps[3072];
  __shared__ u64 topw[768];
  __shared__ double hs[32];
  const int bi = blockIdx.x;
  const int tid = threadIdx.x;

  if (bi == 0) {
    if (tid < 64) {
      const int m = tid & 15, g = tid >> 4;
      const d4 z = {0.0, 0.0, 0.0, 0.0};
      const double e = (g == 0) ? (double)(m + 1) : 0.0;
      d4 r1 = __builtin_amdgcn_mfma_f64_16x16x4f64(e, 1.0, z, 0, 0, 0);
      d4 r2 = __builtin_amdgcn_mfma_f64_16x16x4f64(1.0, e, z, 0, 0, 0);
#pragma unroll
      for (int r = 0; r < 4; ++r) {
        const int row = ((int)r1[r] - 1) & 15;
        const int col = ((int)r2[r] - 1) & 15;
        mtab[tid * 4 + r] = (row << 8) | col;
      }
    }
  } else if (bi < 33) {
    const int idx = bi - 1;
    const int b = idx & 7, part = idx >> 3;
    double acc = 0.0;
    const float* xr = x3 + (size_t)b * GG + part * 256;
    const float* wr = w1 + (size_t)part * 256 * 256;
    for (int k = 0; k < 256; ++k)
      acc += (double)xr[k] * (double)wr[k * 256 + tid];
    y3p[((size_t)b * 4 + part) * 256 + tid] = acc;

    if (part == 0) {
      if (tid < 32) {
        double a = (double)eb1[tid];
        for (int k = 0; k < 3; ++k)
          a += (double)ap[b * 3 + k] * (double)ew1[k * 32 + tid];
        hs[tid] = fmax(a, 0.0);
      }
      __syncthreads();
      if (tid < 32) {
        double a = (double)eb2[tid];
        for (int k = 0; k < 32; ++k)
          a += hs[k] * (double)ew2[k * 32 + tid];
        af[b * 32 + tid] = (float)a;
      }
    }
  } else if (bi < 161) {
    knn_body<N2, N1>(bi - 33, pos2, pos1, idx2, wn2, ps, topw);
  } else {
    knn_body<N1, N0>(bi - 161, pos1, pos0, idx1, wn1, ps, topw);
  }
}

// ---------------------------------------------------------------------------
// fp64-MFMA tile worker, layout-adaptive via probe table rc4. One wave computes
// rows [rb, rb+16) x cols [jb, jb+NT*16) of out = in @ w + bias over K.
//   A slot: a = inL[(rb+m)][k=4s+g];  B slot: bv = w[k][jb + t*16 + m]
//   D slot r -> (rw[r], cl[r]) within the 16x16 tile (from probe).
// K%4 tail: inL cols K.. must be zero-padded; weight load predicated.
template <int NT, int K, int JW, int INS_S, int OUTS_S, bool RELU, bool Y3>
__device__ __forceinline__ void
mfma_tile(const float* __restrict__ inL, float* __restrict__ outP,
          const float* __restrict__ w, const float* __restrict__ bias,
          const double* __restrict__ y3b, int lane, int jb, int rb, int4 rc4) {
  const int m = lane & 15, g = lane >> 4;
  int rw[4], cl[4];
  rw[0] = (rc4.x >> 8) & 15; cl[0] = rc4.x & 15;
  rw[1] = (rc4.y >> 8) & 15; cl[1] = rc4.y & 15;
  rw[2] = (rc4.z >> 8) & 15; cl[2] = rc4.z & 15;
  rw[3] = (rc4.w >> 8) & 15; cl[3] = rc4.w & 15;
  d4 acc[NT];
#pragma unroll
  for (int t = 0; t < NT; ++t) {
#pragma unroll
    for (int r = 0; r < 4; ++r) {
      const int j = jb + t * 16 + cl[r];
      double base = (double)bias[j];
      if (Y3) base += y3b[j] + y3b[256 + j] + y3b[512 + j] + y3b[768 + j];
      acc[t][r] = base;
    }
  }
  constexpr int FULL = K / 4;
#pragma unroll 2
  for (int s = 0; s < FULL; ++s) {
    const double a = (double)inL[(rb + m) * INS_S + 4 * s + g];
    const float* wr = w + (size_t)(4 * s + g) * JW + jb + m;
#pragma unroll
    for (int t = 0; t < NT; ++t) {
      const double bv = (double)wr[t * 16];
      acc[t] = __builtin_amdgcn_mfma_f64_16x16x4f64(a, bv, acc[t], 0, 0, 0);
    }
  }
  if constexpr ((K & 3) != 0) {
    const int kk = FULL * 4 + g;
    const double a = (double)inL[(rb + m) * INS_S + kk];  // zero-padded past K
    const bool ok = kk < K;
    const float* wr = w + (size_t)kk * JW + jb + m;
#pragma unroll
    for (int t = 0; t < NT; ++t) {
      double bv = 0.0;
      if (ok) bv = (double)wr[t * 16];
      acc[t] = __builtin_amdgcn_mfma_f64_16x16x4f64(a, bv, acc[t], 0, 0, 0);
    }
  }
#pragma unroll
  for (int t = 0; t < NT; ++t)
#pragma unroll
    for (int r = 0; r < 4; ++r) {
      float v = (float)acc[t][r];
      if (RELU) v = fmaxf(v, 0.f);
      outP[(size_t)(rb + rw[r]) * OUTS_S + jb + t * 16 + cl[r]] = v;
    }
}

// ---------------------------------------------------------------------------
// k_fp3: 16 points/block, 512 threads (8 waves x NT=2 -> J=256). grid 128.
// t = relu(y3 + x2 @ w1[1024:] + b1); h2 = t @ w2 + b2 (straight to global).
__global__ void __launch_bounds__(512)
k_fp3(const float* __restrict__ x2, const double* __restrict__ y3p,
      const float* __restrict__ w1, const float* __restrict__ b1,
      const float* __restrict__ w2, const float* __restrict__ b2,
      float* __restrict__ h2, const int* __restrict__ mtab) {
  __shared__ float rows[16 * 261];
  __shared__ float t[16 * 261];
  const int b = blockIdx.x >> 4;
  const int p0 = (blockIdx.x & 15) * 16;
  const int tid = threadIdx.x;
  const int lane = tid & 63, wv = tid >> 6;
  const int4 rc4 = *(const int4*)(mtab + lane * 4);
  {
    const int c = tid & 255, ph = tid >> 8;
    for (int i = 0; i < 8; ++i) {
      const int p = i * 2 + ph;
      rows[p * 261 + c] = x2[((size_t)b * N2 + p0 + p) * 256 + c];
    }
  }
  __syncthreads();
  mfma_tile<2, 256, 256, 261, 261, true, true>(rows, t, w1 + (size_t)1024 * 256,
                                               b1, y3p + (size_t)b * 1024,
                                               lane, wv * 32, 0, rc4);
  __syncthreads();
  mfma_tile<2, 256, 256, 261, 256, false, false>(t, h2 + ((size_t)b * N2 + p0) * 256,
                                                 w2, b2, nullptr, lane, wv * 32, 0, rc4);
}

// ---------------------------------------------------------------------------
// k_fp2: 16 points/block, 512 threads (8 waves; L1 NT=2 J=256, L2 NT=1 J=128).
// grid 512. interp(h2,k=3)||x1 -> relu(384->256) -> 256->128 (to global h1).
__global__ void __launch_bounds__(512)
k_fp2(const float* __restrict__ h2, const float* __restrict__ x1,
      const int* __restrict__ idx2, const double* __restrict__ wn2,
      const float* __restrict__ w1, const float* __restrict__ b1,
      const float* __restrict__ w2, const float* __restrict__ b2,
      float* __restrict__ h1, const int* __restrict__ mtab) {
  __shared__ float rows[16 * 389];
  __shared__ float t[16 * 261];
  __shared__ int sidx[16][3];
  __shared__ double swn[16][3];
  const int b = blockIdx.x >> 6;
  const int p0 = (blockIdx.x & 63) * 16;
  const int tid = threadIdx.x;
  const int lane = tid & 63, wv = tid >> 6;
  const int4 rc4 = *(const int4*)(mtab + lane * 4);

  if (tid < 48) {
    const int p = tid / 3, i = tid % 3;
    const size_t g = ((size_t)b * N1 + p0 + p) * 3 + i;
    sidx[p][i] = idx2[g];
    swn[p][i] = wn2[g];
  }
  __syncthreads();

  {
    const float* base = h2 + (size_t)b * N2 * 256;
    const int c = tid & 255, ph = tid >> 8;
    for (int i = 0; i < 8; ++i) {
      const int p = i * 2 + ph;
      const double v = swn[p][0] * (double)base[(size_t)sidx[p][0] * 256 + c] +
                       swn[p][1] * (double)base[(size_t)sidx[p][1] * 256 + c] +
                       swn[p][2] * (double)base[(size_t)sidx[p][2] * 256 + c];
      rows[p * 389 + c] = (float)v;
    }
    const int c2 = tid & 127, p4 = tid >> 7;
    for (int i = 0; i < 4; ++i) {
      const int p = i * 4 + p4;
      rows[p * 389 + 256 + c2] = x1[((size_t)b * N1 + p0 + p) * 128 + c2];
    }
  }
  __syncthreads();
  mfma_tile<2, 384, 256, 389, 261, true, false>(rows, t, w1, b1, nullptr,
                                                lane, wv * 32, 0, rc4);
  __syncthreads();
  mfma_tile<1, 256, 128, 261, 128, false, false>(t, h1 + ((size_t)b * N1 + p0) * 128,
                                                 w2, b2, nullptr, lane, wv * 16, 0, rc4);
}

// ---------------------------------------------------------------------------
// k_fp1head: 32 points/block, 512 threads (8 waves = 2 row-groups x 4 j-groups,
// NT=2, J=128). grid 1024. interp(h1)||pos0 -> [131->128 r] -> [128 r] ->
// [128] -> cat af -> [160->128 r] -> [128 r] -> [128->1].
__global__ void __launch_bounds__(512)
k_fp1head(const float* __restrict__ h1, const float* __restrict__ pos0,
          const int* __restrict__ idx1, const double* __restrict__ wn1,
          const float* __restrict__ afv,
          const float* __restrict__ w1, const float* __restrict__ b1,
          const float* __restrict__ w2, const float* __restrict__ b2,
          const float* __restrict__ w3, const float* __restrict__ b3,
          const float* __restrict__ hw1, const float* __restrict__ hb1,
          const float* __restrict__ hw2, const float* __restrict__ hb2,
          const float* __restrict__ hw3, const float* __restrict__ hb3,
          float* __restrict__ out, const int* __restrict__ mtab) {
  __shared__ float A[32 * 137];   // inputs 131 (+zero pad); also L2/L4 outputs
  __shared__ float Bf[32 * 165];  // L1/L3/L5 outputs; cols 128..159 = af
  __shared__ int sidx[32][3];
  __shared__ double swn[32][3];
  const int b = blockIdx.x >> 7;          // 128 blocks per batch
  const int p0 = (blockIdx.x & 127) * 32;
  const int tid = threadIdx.x;
  const int lane = tid & 63, wv = tid >> 6;
  const int rb = (wv >> 2) * 16;          // row-group 0/1
  const int jb = (wv & 3) * 32;           // j-group 0..3 (NT=2 -> 32 cols)
  const int4 rc4 = *(const int4*)(mtab + lane * 4);

  if (tid < 96) {
    const int p = tid / 3, i = tid % 3;
    const size_t g = ((size_t)b * N0 + p0 + p) * 3 + i;
    sidx[p][i] = idx1[g];
    swn[p][i] = wn1[g];
  }
  if (tid >= 96 && tid < 128) {      // zero-pad A cols 131..136 (L1 K-tail)
    const int p = tid - 96;
    for (int c = 131; c < 137; ++c) A[p * 137 + c] = 0.f;
  }
  for (int x = tid; x < 32 * 32; x += 512)  // af -> Bf cols 128..159
    Bf[(x >> 5) * 165 + 128 + (x & 31)] = afv[b * 32 + (x & 31)];
  __syncthreads();

  {
    const int c = tid & 127, pq = tid >> 7;
    const float* basep = h1 + (size_t)b * N1 * 128;
    for (int i = 0; i < 8; ++i) {
      const int p = i * 4 + pq;
      const double v = swn[p][0] * (double)basep[(size_t)sidx[p][0] * 128 + c] +
                       swn[p][1] * (double)basep[(size_t)sidx[p][1] * 128 + c] +
                       swn[p][2] * (double)basep[(size_t)sidx[p][2] * 128 + c];
      A[p * 137 + c] = (float)v;
    }
  }
  if (tid < 96) {
    const int p = tid / 3, i = tid % 3;
    A[p * 137 + 128 + i] = pos0[((size_t)b * N0 + p0 + p) * 3 + i];
  }
  __syncthreads();

  mfma_tile<2, 131, 128, 137, 165, true,  false>(A,  Bf, w1,  b1,  nullptr, lane, jb, rb, rc4);
  __syncthreads();
  mfma_tile<2, 128, 128, 165, 137, true,  false>(Bf, A,  w2,  b2,  nullptr, lane, jb, rb, rc4);
  __syncthreads();
  mfma_tile<2, 128, 128, 137, 165, false, false>(A,  Bf, w3,  b3,  nullptr, lane, jb, rb, rc4);
  __syncthreads();
  mfma_tile<2, 160, 128, 165, 137, true,  false>(Bf, A,  hw1, hb1, nullptr, lane, jb, rb, rc4);
  __syncthreads();
  mfma_tile<2, 128, 128, 137, 165, true,  false>(A,  Bf, hw2, hb2, nullptr, lane, jb, rb, rc4);
  __syncthreads();

  // head3: fp64 dot, 16 lanes per point (32 points, 512 threads)
  {
    const int p = tid >> 4, l = tid & 15;
    double acc = 0.0;
    for (int k = l; k < 128; k += 16)
      acc += (double)Bf[p * 165 + k] * (double)hw3[k];
    for (int off = 8; off > 0; off >>= 1)
      acc += __shfl_down(acc, off, 16);
    if (l == 0)
      out[(size_t)b * N0 + p0 + p] = (float)(acc + (double)hb3[0]);
  }
}

// ---------------------------------------------------------------------------
extern "C" void kernel_launch(void* const* d_in, const int* in_sizes, int n_in,
                              void* d_out, int out_size, void* d_ws, size_t ws_size,
                              hipStream_t stream) {
  const float* pos0 = (const float*)d_in[0];
  const float* x1   = (const float*)d_in[1];
  const float* pos1 = (const float*)d_in[2];
  const float* x2   = (const float*)d_in[3];
  const float* pos2 = (const float*)d_in[4];
  const float* x3   = (const float*)d_in[5];
  /* d_in[6] = pos3: unused (k=1 interp from a single point is a broadcast) */
  const float* ap   = (const float*)d_in[7];
  const float* fp3w1 = (const float*)d_in[8];
  const float* fp3b1 = (const float*)d_in[9];
  const float* fp3w2 = (const float*)d_in[10];
  const float* fp3b2 = (const float*)d_in[11];
  const float* fp2w1 = (const float*)d_in[12];
  const float* fp2b1 = (const float*)d_in[13];
  const float* fp2w2 = (const float*)d_in[14];
  const float* fp2b2 = (const float*)d_in[15];
  const float* fp1w1 = (const float*)d_in[16];
  const float* fp1b1 = (const float*)d_in[17];
  const float* fp1w2 = (const float*)d_in[18];
  const float* fp1b2 = (const float*)d_in[19];
  const float* fp1w3 = (const float*)d_in[20];
  const float* fp1b3 = (const float*)d_in[21];
  const float* encw1 = (const float*)d_in[22];
  const float* encb1 = (const float*)d_in[23];
  const float* encw2 = (const float*)d_in[24];
  const float* encb2 = (const float*)d_in[25];
  const float* hw1 = (const float*)d_in[26];
  const float* hb1 = (const float*)d_in[27];
  const float* hw2 = (const float*)d_in[28];
  const float* hb2 = (const float*)d_in[29];
  const float* hw3 = (const float*)d_in[30];
  const float* hb3 = (const float*)d_in[31];
  float* out = (float*)d_out;

  // Alias-free layout (+1 KB probe table).
  char* p = (char*)d_ws;
  double* y3p = (double*)p; p += (size_t)BB * 4 * 256 * 8;   // 64 KB
  double* wn2 = (double*)p; p += (size_t)BB * N1 * 3 * 8;    // 192 KB
  double* wn1 = (double*)p; p += (size_t)BB * N0 * 3 * 8;    // 768 KB
  float*  af  = (float*)p;  p += (size_t)BB * 32 * 4;        // 1 KB
  int*    idx2= (int*)p;    p += (size_t)BB * N1 * 3 * 4;    // 96 KB
  int*    idx1= (int*)p;    p += (size_t)BB * N0 * 3 * 4;    // 384 KB
  float*  h2  = (float*)p;  p += (size_t)BB * N2 * 256 * 4;  // 2 MB
  float*  h1  = (float*)p;  p += (size_t)BB * N1 * 128 * 4;  // 4 MB
  int*    mtab= (int*)p;    p += 1024;                        // 64 lanes x 4

  hipLaunchKernelGGL(k_setup, dim3(673), dim3(256), 0, stream,
                     pos0, pos1, pos2, x3, fp3w1, y3p,
                     ap, encw1, encb1, encw2, encb2, af,
                     idx2, wn2, idx1, wn1, mtab);
  hipLaunchKernelGGL(k_fp3, dim3(BB * N2 / 16), dim3(512), 0, stream,
                     x2, y3p, fp3w1, fp3b1, fp3w2, fp3b2, h2, mtab);
  hipLaunchKernelGGL(k_fp2, dim3(BB * N1 / 16), dim3(512), 0, stream,
                     h2, x1, idx2, wn2, fp2w1, fp2b1, fp2w2, fp2b2, h1, mtab);
  hipLaunchKernelGGL(k_fp1head, dim3(BB * N0 / 32), dim3(512), 0, stream,
                     h1, pos0, idx1, wn1, af,
                     fp1w1, fp1b1, fp1w2, fp1b2, fp1w3, fp1b3,
                     hw1, hb1, hw2, hb2, hw3, hb3, out, mtab);
}

// Round 10
// 313.721 us; speedup vs baseline: 1.9063x; 1.0464x over previous
//
#include <hip/hip_runtime.h>

// Sizes (fixed by the problem)
#define BB   8
#define N0   4096
#define N1   1024
#define N2   256
#define GG   1024
#define AFW  32

typedef unsigned long long u64;
typedef double d4 __attribute__((ext_vector_type(4)));

// ---------------------------------------------------------------------------
// Branchless top-3 insert on u64 keys (distance bits | index), stable.
__device__ __forceinline__ void ins3(u64 key, u64& k0, u64& k1, u64& k2) {
  const bool c0 = key < k0, c1 = key < k1, c2 = key < k2;
  const u64 n2 = c1 ? k1 : (c2 ? key : k2);
  const u64 n1 = c0 ? k0 : (c1 ? key : k1);
  k0 = c0 ? key : k0; k1 = n1; k2 = n2;
}

// ---------------------------------------------------------------------------
// knn body: 64 queries x 4 candidate-quarter waves, LDS merge (order-free:
// keys unique). Keys = fp64 d2 bits, low 10 mantissa bits = candidate index.
template <int NCAND, int QTOT>
__device__ __forceinline__ void
knn_body(int idx, const float* __restrict__ cpos, const float* __restrict__ qpos,
         int* __restrict__ idxo, double* __restrict__ wno,
         double* __restrict__ ps, u64* __restrict__ topw) {
  const int qc = idx % (QTOT / 64);
  const int b = idx / (QTOT / 64);
  const int tid = threadIdx.x;
  {
    const float* src = cpos + (size_t)b * NCAND * 3;
    for (int i = tid; i < NCAND * 3; i += 256) ps[i] = (double)src[i];
  }
  __syncthreads();

  const int wave = tid >> 6, lane = tid & 63;
  const size_t gq = (size_t)b * QTOT + qc * 64 + lane;
  const double qx = (double)qpos[gq * 3 + 0];
  const double qy = (double)qpos[gq * 3 + 1];
  const double qz = (double)qpos[gq * 3 + 2];

  constexpr int NC4 = NCAND / 4;
  u64 k0 = ~0ull, k1 = ~0ull, k2 = ~0ull;
  const int kbeg = wave * NC4;
#pragma unroll 2
  for (int kk = 0; kk < NC4; ++kk) {
    const int k = kbeg + kk;
    const double dx = qx - ps[3 * k + 0];
    const double dy = qy - ps[3 * k + 1];
    const double dz = qz - ps[3 * k + 2];
    const double d = dx * dx + dy * dy + dz * dz;
    const u64 key = (((u64)__double_as_longlong(d)) & ~1023ull) | (unsigned)k;
    ins3(key, k0, k1, k2);
  }
  topw[(wave * 64 + lane) * 3 + 0] = k0;
  topw[(wave * 64 + lane) * 3 + 1] = k1;
  topw[(wave * 64 + lane) * 3 + 2] = k2;
  __syncthreads();

  if (tid < 64) {
    u64 m0 = ~0ull, m1 = ~0ull, m2 = ~0ull;
#pragma unroll
    for (int w = 0; w < 4; ++w)
#pragma unroll
      for (int s = 0; s < 3; ++s)
        ins3(topw[(w * 64 + tid) * 3 + s], m0, m1, m2);
    const double d0 = __longlong_as_double((long long)(m0 & ~1023ull));
    const double d1 = __longlong_as_double((long long)(m1 & ~1023ull));
    const double d2 = __longlong_as_double((long long)(m2 & ~1023ull));
    const double w0 = 1.0 / fmax(d0, 1e-16);
    const double w1 = 1.0 / fmax(d1, 1e-16);
    const double w2 = 1.0 / fmax(d2, 1e-16);
    const double inv = 1.0 / (w0 + w1 + w2);
    const size_t go = (size_t)b * QTOT + qc * 64 + tid;
    idxo[go * 3 + 0] = (int)(m0 & 1023ull);
    idxo[go * 3 + 1] = (int)(m1 & 1023ull);
    idxo[go * 3 + 2] = (int)(m2 & 1023ull);
    wno[go * 3 + 0] = w0 * inv;
    wno[go * 3 + 1] = w1 * inv;
    wno[go * 3 + 2] = w2 * inv;
  }
}

// ---------------------------------------------------------------------------
// k_setup: fused {probe | y3_enc | knn2 | knn1} via blockIdx ranges.
__global__ void __launch_bounds__(256)
k_setup(const float* __restrict__ pos0, const float* __restrict__ pos1,
        const float* __restrict__ pos2,
        const float* __restrict__ x3, const float* __restrict__ w1,
        double* __restrict__ y3p,
        const float* __restrict__ ap,
        const float* __restrict__ ew1, const float* __restrict__ eb1,
        const float* __restrict__ ew2, const float* __restrict__ eb2,
        float* __restrict__ af,
        int* __restrict__ idx2, double* __restrict__ wn2,
        int* __restrict__ idx1, double* __restrict__ wn1,
        int* __restrict__ mtab) {
  __shared__ double ps[3072];
  __shared__ u64 topw[768];
  __shared__ double hs[32];
  const int bi = blockIdx.x;
  const int tid = threadIdx.x;

  if (bi == 0) {
    if (tid < 64) {
      const int m = tid & 15, g = tid >> 4;
      const d4 z = {0.0, 0.0, 0.0, 0.0};
      const double e = (g == 0) ? (double)(m + 1) : 0.0;
      d4 r1 = __builtin_amdgcn_mfma_f64_16x16x4f64(e, 1.0, z, 0, 0, 0);
      d4 r2 = __builtin_amdgcn_mfma_f64_16x16x4f64(1.0, e, z, 0, 0, 0);
#pragma unroll
      for (int r = 0; r < 4; ++r) {
        const int row = ((int)r1[r] - 1) & 15;
        const int col = ((int)r2[r] - 1) & 15;
        mtab[tid * 4 + r] = (row << 8) | col;
      }
    }
  } else if (bi < 33) {
    const int idx = bi - 1;
    const int b = idx & 7, part = idx >> 3;
    double acc = 0.0;
    const float* xr = x3 + (size_t)b * GG + part * 256;
    const float* wr = w1 + (size_t)part * 256 * 256;
    for (int k = 0; k < 256; ++k)
      acc += (double)xr[k] * (double)wr[k * 256 + tid];
    y3p[((size_t)b * 4 + part) * 256 + tid] = acc;

    if (part == 0) {
      if (tid < 32) {
        double a = (double)eb1[tid];
        for (int k = 0; k < 3; ++k)
          a += (double)ap[b * 3 + k] * (double)ew1[k * 32 + tid];
        hs[tid] = fmax(a, 0.0);
      }
      __syncthreads();
      if (tid < 32) {
        double a = (double)eb2[tid];
        for (int k = 0; k < 32; ++k)
          a += hs[k] * (double)ew2[k * 32 + tid];
        af[b * 32 + tid] = (float)a;
      }
    }
  } else if (bi < 161) {
    knn_body<N2, N1>(bi - 33, pos2, pos1, idx2, wn2, ps, topw);
  } else {
    knn_body<N1, N0>(bi - 161, pos1, pos0, idx1, wn1, ps, topw);
  }
}

// ---------------------------------------------------------------------------
// fp64-MFMA tile worker with distance-2 weight prefetch. One wave computes
// rows [rb, rb+16) x cols [jb, jb+NT*16) of out = in @ w + bias over K.
//   A slot: a = inL[(rb+m)][k=4s+g];  B slot: bv = w[k][jb + t*16 + m]
//   D slot r -> (rw[r], cl[r]) within the 16x16 tile (from probe table).
// FULL = K/4 is even for every layer here; K%4 tail (K=131) predicated.
// Numerics: bias-first, k ascending, groups of 4 — identical to round 9.
template <int NT, int K, int JW, int INS_S, int OUTS_S, bool RELU, bool Y3>
__device__ __forceinline__ void
mfma_tile(const float* __restrict__ inL, float* __restrict__ outP,
          const float* __restrict__ w, const float* __restrict__ bias,
          const double* __restrict__ y3b, int lane, int jb, int rb, int4 rc4) {
  const int m = lane & 15, g = lane >> 4;
  int rw[4], cl[4];
  rw[0] = (rc4.x >> 8) & 15; cl[0] = rc4.x & 15;
  rw[1] = (rc4.y >> 8) & 15; cl[1] = rc4.y & 15;
  rw[2] = (rc4.z >> 8) & 15; cl[2] = rc4.z & 15;
  rw[3] = (rc4.w >> 8) & 15; cl[3] = rc4.w & 15;
  d4 acc[NT];
#pragma unroll
  for (int t = 0; t < NT; ++t) {
#pragma unroll
    for (int r = 0; r < 4; ++r) {
      const int j = jb + t * 16 + cl[r];
      double base = (double)bias[j];
      if (Y3) base += y3b[j] + y3b[256 + j] + y3b[512 + j] + y3b[768 + j];
      acc[t][r] = base;
    }
  }
  constexpr int FULL = K / 4;          // even for all layers used
  const float* wbase = w + (size_t)g * JW + jb + m;
  double b0[NT], b1[NT];
#pragma unroll
  for (int t = 0; t < NT; ++t) {
    b0[t] = (double)wbase[t * 16];                         // s=0
    b1[t] = (double)wbase[(size_t)4 * JW + t * 16];        // s=1
  }
  for (int s = 0; s < FULL; s += 2) {
    double n0[NT], n1[NT];
    const bool more = (s + 2) < FULL;
    if (more) {
#pragma unroll
      for (int t = 0; t < NT; ++t) {
        n0[t] = (double)wbase[(size_t)(4 * (s + 2)) * JW + t * 16];
        n1[t] = (double)wbase[(size_t)(4 * (s + 3)) * JW + t * 16];
      }
    }
    const double a0 = (double)inL[(rb + m) * INS_S + 4 * s + g];
#pragma unroll
    for (int t = 0; t < NT; ++t)
      acc[t] = __builtin_amdgcn_mfma_f64_16x16x4f64(a0, b0[t], acc[t], 0, 0, 0);
    const double a1 = (double)inL[(rb + m) * INS_S + 4 * (s + 1) + g];
#pragma unroll
    for (int t = 0; t < NT; ++t)
      acc[t] = __builtin_amdgcn_mfma_f64_16x16x4f64(a1, b1[t], acc[t], 0, 0, 0);
    if (more) {
#pragma unroll
      for (int t = 0; t < NT; ++t) { b0[t] = n0[t]; b1[t] = n1[t]; }
    }
  }
  if constexpr ((K & 3) != 0) {
    const int kk = FULL * 4 + g;
    const double a = (double)inL[(rb + m) * INS_S + kk];  // zero-padded past K
    const bool ok = kk < K;
    const float* wr = w + (size_t)kk * JW + jb + m;
#pragma unroll
    for (int t = 0; t < NT; ++t) {
      double bv = 0.0;
      if (ok) bv = (double)wr[t * 16];
      acc[t] = __builtin_amdgcn_mfma_f64_16x16x4f64(a, bv, acc[t], 0, 0, 0);
    }
  }
#pragma unroll
  for (int t = 0; t < NT; ++t)
#pragma unroll
    for (int r = 0; r < 4; ++r) {
      float v = (float)acc[t][r];
      if (RELU) v = fmaxf(v, 0.f);
      outP[(size_t)(rb + rw[r]) * OUTS_S + jb + t * 16 + cl[r]] = v;
    }
}

// ---------------------------------------------------------------------------
// k_fp3a: L1 of fp3, J-split. grid 256 = (pgroup 0..127) x (jhalf 0..1).
// Block: 256 thr, 4 waves, 16 points, NT=2 -> 128 cols per block.
// t3 = relu(y3 + x2 @ w1[1024:] + b1)  (fp32 to global, same rounding as LDS)
__global__ void __launch_bounds__(256)
k_fp3a(const float* __restrict__ x2, const double* __restrict__ y3p,
       const float* __restrict__ w1, const float* __restrict__ b1,
       float* __restrict__ t3, const int* __restrict__ mtab) {
  __shared__ float rows[16 * 261];
  const int jh = blockIdx.x & 1;
  const int pg = blockIdx.x >> 1;
  const int b = pg >> 4;
  const int p0 = (pg & 15) * 16;
  const int tid = threadIdx.x;
  const int lane = tid & 63, wv = tid >> 6;
  const int4 rc4 = *(const int4*)(mtab + lane * 4);
  for (int p = 0; p < 16; ++p)
    rows[p * 261 + tid] = x2[((size_t)b * N2 + p0 + p) * 256 + tid];
  __syncthreads();
  mfma_tile<2, 256, 256, 261, 256, true, true>(
      rows, t3 + ((size_t)b * N2 + p0) * 256, w1 + (size_t)1024 * 256, b1,
      y3p + (size_t)b * 1024, lane, jh * 128 + wv * 32, 0, rc4);
}

// k_fp3b: L2 of fp3, J-split. grid 256. h2 = t3 @ w2 + b2.
__global__ void __launch_bounds__(256)
k_fp3b(const float* __restrict__ t3,
       const float* __restrict__ w2, const float* __restrict__ b2,
       float* __restrict__ h2, const int* __restrict__ mtab) {
  __shared__ float rows[16 * 261];
  const int jh = blockIdx.x & 1;
  const int pg = blockIdx.x >> 1;
  const int b = pg >> 4;
  const int p0 = (pg & 15) * 16;
  const int tid = threadIdx.x;
  const int lane = tid & 63, wv = tid >> 6;
  const int4 rc4 = *(const int4*)(mtab + lane * 4);
  for (int p = 0; p < 16; ++p)
    rows[p * 261 + tid] = t3[((size_t)b * N2 + p0 + p) * 256 + tid];
  __syncthreads();
  mfma_tile<2, 256, 256, 261, 256, false, false>(
      rows, h2 + ((size_t)b * N2 + p0) * 256, w2, b2, nullptr,
      lane, jh * 128 + wv * 32, 0, rc4);
}

// ---------------------------------------------------------------------------
// k_fp2: 16 points/block, 512 threads (8 waves; L1 NT=2 J=256, L2 NT=1 J=128).
// grid 512. interp(h2,k=3)||x1 -> relu(384->256) -> 256->128 (to global h1).
__global__ void __launch_bounds__(512)
k_fp2(const float* __restrict__ h2, const float* __restrict__ x1,
      const int* __restrict__ idx2, const double* __restrict__ wn2,
      const float* __restrict__ w1, const float* __restrict__ b1,
      const float* __restrict__ w2, const float* __restrict__ b2,
      float* __restrict__ h1, const int* __restrict__ mtab) {
  __shared__ float rows[16 * 389];
  __shared__ float t[16 * 261];
  __shared__ int sidx[16][3];
  __shared__ double swn[16][3];
  const int b = blockIdx.x >> 6;
  const int p0 = (blockIdx.x & 63) * 16;
  const int tid = threadIdx.x;
  const int lane = tid & 63, wv = tid >> 6;
  const int4 rc4 = *(const int4*)(mtab + lane * 4);

  if (tid < 48) {
    const int p = tid / 3, i = tid % 3;
    const size_t g = ((size_t)b * N1 + p0 + p) * 3 + i;
    sidx[p][i] = idx2[g];
    swn[p][i] = wn2[g];
  }
  __syncthreads();

  {
    const float* base = h2 + (size_t)b * N2 * 256;
    const int c = tid & 255, ph = tid >> 8;
    for (int i = 0; i < 8; ++i) {
      const int p = i * 2 + ph;
      const double v = swn[p][0] * (double)base[(size_t)sidx[p][0] * 256 + c] +
                       swn[p][1] * (double)base[(size_t)sidx[p][1] * 256 + c] +
                       swn[p][2] * (double)base[(size_t)sidx[p][2] * 256 + c];
      rows[p * 389 + c] = (float)v;
    }
    const int c2 = tid & 127, p4 = tid >> 7;
    for (int i = 0; i < 4; ++i) {
      const int p = i * 4 + p4;
      rows[p * 389 + 256 + c2] = x1[((size_t)b * N1 + p0 + p) * 128 + c2];
    }
  }
  __syncthreads();
  mfma_tile<2, 384, 256, 389, 261, true, false>(rows, t, w1, b1, nullptr,
                                                lane, wv * 32, 0, rc4);
  __syncthreads();
  mfma_tile<1, 256, 128, 261, 128, false, false>(t, h1 + ((size_t)b * N1 + p0) * 128,
                                                 w2, b2, nullptr, lane, wv * 16, 0, rc4);
}

// ---------------------------------------------------------------------------
// k_fp1head: 32 points/block, 512 threads (8 waves = 2 row-groups x 4 j-groups,
// NT=2, J=128). grid 1024. interp(h1)||pos0 -> [131->128 r] -> [128 r] ->
// [128] -> cat af -> [160->128 r] -> [128 r] -> [128->1].
__global__ void __launch_bounds__(512)
k_fp1head(const float* __restrict__ h1, const float* __restrict__ pos0,
          const int* __restrict__ idx1, const double* __restrict__ wn1,
          const float* __restrict__ afv,
          const float* __restrict__ w1, const float* __restrict__ b1,
          const float* __restrict__ w2, const float* __restrict__ b2,
          const float* __restrict__ w3, const float* __restrict__ b3,
          const float* __restrict__ hw1, const float* __restrict__ hb1,
          const float* __restrict__ hw2, const float* __restrict__ hb2,
          const float* __restrict__ hw3, const float* __restrict__ hb3,
          float* __restrict__ out, const int* __restrict__ mtab) {
  __shared__ float A[32 * 137];   // inputs 131 (+zero pad); also L2/L4 outputs
  __shared__ float Bf[32 * 165];  // L1/L3/L5 outputs; cols 128..159 = af
  __shared__ int sidx[32][3];
  __shared__ double swn[32][3];
  const int b = blockIdx.x >> 7;          // 128 blocks per batch
  const int p0 = (blockIdx.x & 127) * 32;
  const int tid = threadIdx.x;
  const int lane = tid & 63, wv = tid >> 6;
  const int rb = (wv >> 2) * 16;          // row-group 0/1
  const int jb = (wv & 3) * 32;           // j-group 0..3 (NT=2 -> 32 cols)
  const int4 rc4 = *(const int4*)(mtab + lane * 4);

  if (tid < 96) {
    const int p = tid / 3, i = tid % 3;
    const size_t g = ((size_t)b * N0 + p0 + p) * 3 + i;
    sidx[p][i] = idx1[g];
    swn[p][i] = wn1[g];
  }
  if (tid >= 96 && tid < 128) {      // zero-pad A cols 131..136 (L1 K-tail)
    const int p = tid - 96;
    for (int c = 131; c < 137; ++c) A[p * 137 + c] = 0.f;
  }
  for (int x = tid; x < 32 * 32; x += 512)  // af -> Bf cols 128..159
    Bf[(x >> 5) * 165 + 128 + (x & 31)] = afv[b * 32 + (x & 31)];
  __syncthreads();

  {
    const int c = tid & 127, pq = tid >> 7;
    const float* basep = h1 + (size_t)b * N1 * 128;
    for (int i = 0; i < 8; ++i) {
      const int p = i * 4 + pq;
      const double v = swn[p][0] * (double)basep[(size_t)sidx[p][0] * 128 + c] +
                       swn[p][1] * (double)basep[(size_t)sidx[p][1] * 128 + c] +
                       swn[p][2] * (double)basep[(size_t)sidx[p][2] * 128 + c];
      A[p * 137 + c] = (float)v;
    }
  }
  if (tid < 96) {
    const int p = tid / 3, i = tid % 3;
    A[p * 137 + 128 + i] = pos0[((size_t)b * N0 + p0 + p) * 3 + i];
  }
  __syncthreads();

  mfma_tile<2, 131, 128, 137, 165, true,  false>(A,  Bf, w1,  b1,  nullptr, lane, jb, rb, rc4);
  __syncthreads();
  mfma_tile<2, 128, 128, 165, 137, true,  false>(Bf, A,  w2,  b2,  nullptr, lane, jb, rb, rc4);
  __syncthreads();
  mfma_tile<2, 128, 128, 137, 165, false, false>(A,  Bf, w3,  b3,  nullptr, lane, jb, rb, rc4);
  __syncthreads();
  mfma_tile<2, 160, 128, 165, 137, true,  false>(Bf, A,  hw1, hb1, nullptr, lane, jb, rb, rc4);
  __syncthreads();
  mfma_tile<2, 128, 128, 137, 165, true,  false>(A,  Bf, hw2, hb2, nullptr, lane, jb, rb, rc4);
  __syncthreads();

  // head3: fp64 dot, 16 lanes per point (32 points, 512 threads)
  {
    const int p = tid >> 4, l = tid & 15;
    double acc = 0.0;
    for (int k = l; k < 128; k += 16)
      acc += (double)Bf[p * 165 + k] * (double)hw3[k];
    for (int off = 8; off > 0; off >>= 1)
      acc += __shfl_down(acc, off, 16);
    if (l == 0)
      out[(size_t)b * N0 + p0 + p] = (float)(acc + (double)hb3[0]);
  }
}

// ---------------------------------------------------------------------------
extern "C" void kernel_launch(void* const* d_in, const int* in_sizes, int n_in,
                              void* d_out, int out_size, void* d_ws, size_t ws_size,
                              hipStream_t stream) {
  const float* pos0 = (const float*)d_in[0];
  const float* x1   = (const float*)d_in[1];
  const float* pos1 = (const float*)d_in[2];
  const float* x2   = (const float*)d_in[3];
  const float* pos2 = (const float*)d_in[4];
  const float* x3   = (const float*)d_in[5];
  /* d_in[6] = pos3: unused (k=1 interp from a single point is a broadcast) */
  const float* ap   = (const float*)d_in[7];
  const float* fp3w1 = (const float*)d_in[8];
  const float* fp3b1 = (const float*)d_in[9];
  const float* fp3w2 = (const float*)d_in[10];
  const float* fp3b2 = (const float*)d_in[11];
  const float* fp2w1 = (const float*)d_in[12];
  const float* fp2b1 = (const float*)d_in[13];
  const float* fp2w2 = (const float*)d_in[14];
  const float* fp2b2 = (const float*)d_in[15];
  const float* fp1w1 = (const float*)d_in[16];
  const float* fp1b1 = (const float*)d_in[17];
  const float* fp1w2 = (const float*)d_in[18];
  const float* fp1b2 = (const float*)d_in[19];
  const float* fp1w3 = (const float*)d_in[20];
  const float* fp1b3 = (const float*)d_in[21];
  const float* encw1 = (const float*)d_in[22];
  const float* encb1 = (const float*)d_in[23];
  const float* encw2 = (const float*)d_in[24];
  const float* encb2 = (const float*)d_in[25];
  const float* hw1 = (const float*)d_in[26];
  const float* hb1 = (const float*)d_in[27];
  const float* hw2 = (const float*)d_in[28];
  const float* hb2 = (const float*)d_in[29];
  const float* hw3 = (const float*)d_in[30];
  const float* hb3 = (const float*)d_in[31];
  float* out = (float*)d_out;

  // Alias-free layout (+1 KB probe table). t3 aliases h1: t3 is produced by
  // k_fp3a and fully consumed by k_fp3b BEFORE k_fp2 writes h1 (stream order).
  char* p = (char*)d_ws;
  double* y3p = (double*)p; p += (size_t)BB * 4 * 256 * 8;   // 64 KB
  double* wn2 = (double*)p; p += (size_t)BB * N1 * 3 * 8;    // 192 KB
  double* wn1 = (double*)p; p += (size_t)BB * N0 * 3 * 8;    // 768 KB
  float*  af  = (float*)p;  p += (size_t)BB * 32 * 4;        // 1 KB
  int*    idx2= (int*)p;    p += (size_t)BB * N1 * 3 * 4;    // 96 KB
  int*    idx1= (int*)p;    p += (size_t)BB * N0 * 3 * 4;    // 384 KB
  float*  h2  = (float*)p;  p += (size_t)BB * N2 * 256 * 4;  // 2 MB
  float*  h1  = (float*)p;  p += (size_t)BB * N1 * 128 * 4;  // 4 MB
  int*    mtab= (int*)p;    p += 1024;                        // 64 lanes x 4
  float*  t3  = h1;  // 2 MB alias, dead before h1 is written

  hipLaunchKernelGGL(k_setup, dim3(673), dim3(256), 0, stream,
                     pos0, pos1, pos2, x3, fp3w1, y3p,
                     ap, encw1, encb1, encw2, encb2, af,
                     idx2, wn2, idx1, wn1, mtab);
  hipLaunchKernelGGL(k_fp3a, dim3(256), dim3(256), 0, stream,
                     x2, y3p, fp3w1, fp3b1, t3, mtab);
  hipLaunchKernelGGL(k_fp3b, dim3(256), dim3(256), 0, stream,
                     t3, fp3w2, fp3b2, h2, mtab);
  hipLaunchKernelGGL(k_fp2, dim3(BB * N1 / 16), dim3(512), 0, stream,
                     h2, x1, idx2, wn2, fp2w1, fp2b1, fp2w2, fp2b2, h1, mtab);
  hipLaunchKernelGGL(k_fp1head, dim3(BB * N0 / 32), dim3(512), 0, stream,
                     h1, pos0, idx1, wn1, af,
                     fp1w1, fp1b1, fp1w2, fp1b2, fp1w3, fp1b3,
                     hw1, hb1, hw2, hb2, hw3, hb3, out, mtab);
}